// Round 16
// baseline (324.095 us; speedup 1.0000x reference)
//
#include <hip/hip_runtime.h>
#include <hip/hip_fp16.h>
#include <math.h>

typedef unsigned int uint;
typedef unsigned short ushort;

#define B_ 256
#define T_ 512
#define F_ 378
#define C_ 128
#define H_ 64
#define KPAD 1152   // 3 * 384

using f32x4 = __attribute__((ext_vector_type(4))) float;
using bf16x8 = __attribute__((ext_vector_type(8))) short;
using f16x8 = __attribute__((ext_vector_type(8))) _Float16;

__device__ __forceinline__ ushort f2bf(float f) {
  union { float f; uint u; } c; c.f = f;
  uint r = (c.u + 0x7fffu + ((c.u >> 16) & 1u)) >> 16;
  return (ushort)r;
}
__device__ __forceinline__ uint packbf2(float a, float b) {
  return (uint)f2bf(a) | (((uint)f2bf(b)) << 16);
}
__device__ __forceinline__ ushort f2h(float f) {
  __half h = __float2half(f);
  return *(ushort*)&h;
}
__device__ __forceinline__ float h2f(ushort u) {
  __half h;
  *(ushort*)&h = u;
  return __half2float(h);
}
#define SC_SIG -1.442695041f
#define SC_TANH 2.885390082f

// ---------------- pack conv w -> wbT[c][kk], kk = k*384+f, bf16 ------------
__global__ __launch_bounds__(256) void pack_w_kernel(
    const float* __restrict__ w, ushort* __restrict__ wbT) {
  int i = blockIdx.x * 256 + threadIdx.x;
  if (i >= C_ * KPAD) return;
  int c = i / KPAD, kk = i - c * KPAD;
  int k = kk / 384, f = kk - k * 384;
  float v = (f < F_) ? w[c * (F_ * 3) + f * 3 + k] : 0.f;
  wbT[i] = f2bf(v);
}

// ---- pack w_ih -> wP[dir][g''][128] bf16, PRE-SCALED (R12 g'' order) ------
__global__ __launch_bounds__(256) void pack_wiP_kernel(
    const float* __restrict__ wf, const float* __restrict__ wb,
    ushort* __restrict__ wP) {
  int i = blockIdx.x * 256 + threadIdx.x;  // 2*256*128 = 65536
  int dir = i >> 15, rem = i & 32767;
  int gp = rem >> 7, k = rem & 127;
  int e = gp & 3, n = (gp >> 2) & 3, q = (gp >> 4) & 3, w = gp >> 6;
  int u = 16 * w + 4 * q + n;
  const float* src = dir ? wb : wf;
  float scale = (e == 2) ? SC_TANH : SC_SIG;
  wP[i] = f2bf(src[(e * 64 + u) * 128 + k] * scale);
}

// ---- pack w_hh -> whhP[dir][r][64] FP16, PRE-SCALED (4-wave mapping) ------
__global__ __launch_bounds__(256) void pack_whhP_kernel(
    const float* __restrict__ wf, const float* __restrict__ wb,
    ushort* __restrict__ whhP) {
  int i = blockIdx.x * 256 + threadIdx.x;  // 2*256*64 = 32768
  if (i >= 32768) return;
  int dir = i >> 14, rem = i & 16383;
  int r = rem >> 6, k = rem & 63;
  int e = r & 3, q = (r >> 2) & 3, n = (r >> 4) & 3, w = r >> 6;
  int u = 16 * w + 4 * q + n;
  const float* src = dir ? wb : wf;
  float scale = (e == 2) ? SC_TANH : SC_SIG;
  whhP[i] = f2h(src[(e * 64 + u) * 64 + k] * scale);
}

// ---- pack bias -> biasP[dir][g''] fp32, same order+scale as wP ------------
__global__ __launch_bounds__(256) void pack_biasP_kernel(
    const float* __restrict__ bf, const float* __restrict__ bb,
    float* __restrict__ biasP) {
  int i = blockIdx.x * 256 + threadIdx.x;  // 512
  if (i >= 512) return;
  int dir = i >> 8, gp = i & 255;
  int e = gp & 3, n = (gp >> 2) & 3, q = (gp >> 4) & 3, w = gp >> 6;
  int u = 16 * w + 4 * q + n;
  const float* src = dir ? bb : bf;
  float scale = (e == 2) ? SC_TANH : SC_SIG;
  biasP[i] = src[e * 64 + u] * scale;
}

// ---------------- FUSED Conv1d + xg GEMM ----------------------------------
// Phase 1: conv via implicit GEMM -> y tile bf16 staged in bsb[0:32K).
// Phase 2: 8 chunks x {wreg->xsb, prefetch next wP chunk to regs, MFMA
// (bias C-init), transpose -> tbuf (160B stride: quarters land on disjoint
// bank octets -> conflict-free), coalesced store}. wP L2 latency hides
// under the previous chunk's MFMA instead of sitting between barriers.
__global__ __launch_bounds__(256, 2) void conv_xg_kernel(
    const float* __restrict__ x, const ushort* __restrict__ wbT,
    const float* __restrict__ bias, const ushort* __restrict__ wP,
    const float* __restrict__ biasP, ushort* __restrict__ xgP) {
  __shared__ __align__(16) char xsb[130 * 128];  // conv-A / wP chunk
  __shared__ __align__(16) char bsb[53248];      // conv-B / y tile + tbuf
  const int tid = threadIdx.x;
  const int lane = tid & 63;
  const int wr = (tid >> 7) & 1;
  const int wc = (tid >> 6) & 1;
  const int w = tid >> 6;
  const int b = blockIdx.x >> 2;
  const int t0 = (blockIdx.x & 3) << 7;

  f32x4 acc[4][4];
#pragma unroll
  for (int m = 0; m < 4; ++m)
#pragma unroll
    for (int n = 0; n < 4; ++n) acc[m][n] = (f32x4)(0.f);

  for (int fs = 0; fs < 6; ++fs) {
    __syncthreads();
    {
      auto stage_a = [&](int r, int h) {
        const int t = t0 - 1 + r;
        const bool ok = (t >= 0) && (t < T_);
        const float* srow = x + ((long)b * T_ + (ok ? t : 0)) * F_;
        const int fb = fs * 64 + h * 32;
        char* dst = xsb + r * 128;
        const int sw = (r & 7) << 4;
        uint pk[16];
        if (ok && fb + 31 < F_) {
#pragma unroll
          for (int j = 0; j < 16; ++j) {
            float2 v = *(const float2*)(srow + fb + 2 * j);
            pk[j] = packbf2(v.x, v.y);
          }
        } else {
#pragma unroll
          for (int j = 0; j < 16; ++j) {
            const int f = fb + 2 * j;
            float a = (ok && f < F_) ? srow[f] : 0.f;
            float c2 = (ok && f + 1 < F_) ? srow[f + 1] : 0.f;
            pk[j] = packbf2(a, c2);
          }
        }
#pragma unroll
        for (int j = 0; j < 4; ++j) {
          uint4 p = {pk[4 * j], pk[4 * j + 1], pk[4 * j + 2], pk[4 * j + 3]};
          *(uint4*)(dst + ((h * 64 + j * 16) ^ sw)) = p;
        }
      };
      stage_a(tid >> 1, tid & 1);
      if (tid < 4) stage_a(128 + (tid >> 1), tid & 1);
    }
    {
      const int c = tid >> 1, h = tid & 1;
      const ushort* src = wbT + c * KPAD + fs * 64 + h * 32;
      char* drow = bsb + c * 384;
      const int sw = (c & 7) << 4;
#pragma unroll
      for (int k = 0; k < 3; ++k)
#pragma unroll
        for (int j = 0; j < 4; ++j) {
          uint4 v = *(const uint4*)(src + k * 384 + j * 8);
          *(uint4*)(drow + k * 128 + ((h * 64 + j * 16) ^ sw)) = v;
        }
    }
    __syncthreads();

#pragma unroll
    for (int k = 0; k < 3; ++k) {
#pragma unroll
      for (int s = 0; s < 2; ++s) {
        bf16x8 af[4], bfx[4];
        const int ksub = s * 64 + ((lane >> 4) << 4);
#pragma unroll
        for (int m = 0; m < 4; ++m) {
          const int rr = wr * 64 + m * 16 + (lane & 15) + k;
          af[m] = *(const bf16x8*)(xsb + rr * 128 + (ksub ^ ((rr & 7) << 4)));
        }
#pragma unroll
        for (int n = 0; n < 4; ++n) {
          const int c = wc * 64 + n * 16 + (lane & 15);
          bfx[n] =
              *(const bf16x8*)(bsb + c * 384 + k * 128 + (ksub ^ ((c & 7) << 4)));
        }
#pragma unroll
        for (int m = 0; m < 4; ++m)
#pragma unroll
          for (int n = 0; n < 4; ++n)
            acc[m][n] = __builtin_amdgcn_mfma_f32_16x16x32_bf16(
                af[m], bfx[n], acc[m][n], 0, 0, 0);
      }
    }
  }

  // prefetch wP chunk 0 into regs (loads fly during the epilogue)
  uint4 wreg[4];
  {
    const int rr = tid >> 2, h4 = tid & 3;
    const ushort* src = wP + (long)rr * 128 + h4 * 32;
#pragma unroll
    for (int j = 0; j < 4; ++j) wreg[j] = *(const uint4*)(src + 8 * j);
  }

  // conv epilogue: bias+ReLU -> y tile (bf16, swizzled 256B rows) in bsb
  __syncthreads();
  {
    float bc[4];
#pragma unroll
    for (int n = 0; n < 4; ++n) bc[n] = bias[wc * 64 + n * 16 + (lane & 15)];
#pragma unroll
    for (int m = 0; m < 4; ++m) {
#pragma unroll
      for (int n = 0; n < 4; ++n) {
        const int col = wc * 64 + n * 16 + (lane & 15);
#pragma unroll
        for (int r = 0; r < 4; ++r) {
          const int row = wr * 64 + m * 16 + ((lane >> 4) << 2) + r;
          float v = acc[m][n][r] + bc[n];
          v = v > 0.f ? v : 0.f;
          *(ushort*)(bsb + row * 256 + ((col * 2) ^ ((row & 7) << 4))) =
              f2bf(v);
        }
      }
    }
  }

  // ---- phase 2: xg chunks. xg[t][g''] = y @ wP^T + biasP, fp16 ----
  const long m0 = (long)b * T_ + t0;
  char* const tbuf = bsb + 32768;  // 128 rows x 160B (conflict-free)
#pragma unroll 1
  for (int ch = 0; ch < 8; ++ch) {
    const int dirq = ch >> 2;
    const int g64 = ch & 3;
    const int gbase = dirq * 256 + g64 * 64;
    __syncthreads();  // prev MFMA done with xsb; prev stores done with tbuf
    // write prefetched wP chunk -> xsb (256B/row, swizzled)
    {
      const int rr = tid >> 2, h4 = tid & 3;
      char* drow = xsb + rr * 256;
      const int sw = (rr & 7) << 4;
#pragma unroll
      for (int j = 0; j < 4; ++j)
        *(uint4*)(drow + ((h4 * 64 + j * 16) ^ sw)) = wreg[j];
    }
    // issue next chunk's loads (hide L2 latency under this chunk's MFMA)
    if (ch < 7) {
      const int chn = ch + 1;
      const int gb2 = (chn >> 2) * 256 + (chn & 3) * 64;
      const int rr = tid >> 2, h4 = tid & 3;
      const ushort* src = wP + (long)(gb2 + rr) * 128 + h4 * 32;
#pragma unroll
      for (int j = 0; j < 4; ++j) wreg[j] = *(const uint4*)(src + 8 * j);
    }
    __syncthreads();  // wP chunk ready
    // GEMM: wave w owns m-tiles {2w, 2w+1}; 4 n-tiles; K=128 (4 ks)
    f32x4 xacc[2][4];
#pragma unroll
    for (int n = 0; n < 4; ++n) {
      const float bcv = biasP[gbase + n * 16 + (lane & 15)];
      xacc[0][n] = (f32x4)(bcv);
      xacc[1][n] = (f32x4)(bcv);
    }
#pragma unroll
    for (int ks = 0; ks < 4; ++ks) {
      const int ksub = ks * 64 + ((lane >> 4) << 4);
      bf16x8 af[2], bfx[4];
#pragma unroll
      for (int mm = 0; mm < 2; ++mm) {
        const int rr = (w * 2 + mm) * 16 + (lane & 15);
        af[mm] = *(const bf16x8*)(bsb + rr * 256 + (ksub ^ ((rr & 7) << 4)));
      }
#pragma unroll
      for (int n = 0; n < 4; ++n) {
        const int rb = n * 16 + (lane & 15);
        bfx[n] = *(const bf16x8*)(xsb + rb * 256 + (ksub ^ ((rb & 7) << 4)));
      }
#pragma unroll
      for (int mm = 0; mm < 2; ++mm)
#pragma unroll
        for (int n = 0; n < 4; ++n)
          xacc[mm][n] = __builtin_amdgcn_mfma_f32_16x16x32_bf16(
              af[mm], bfx[n], xacc[mm][n], 0, 0, 0);
    }
    // transpose into tbuf: [128 t][160B stride] fp16, NO swizzle
#pragma unroll
    for (int mm = 0; mm < 2; ++mm) {
#pragma unroll
      for (int n = 0; n < 4; ++n) {
        const int col = n * 16 + (lane & 15);
#pragma unroll
        for (int rA = 0; rA < 4; ++rA) {
          const int row = (w * 2 + mm) * 16 + ((lane >> 4) << 2) + rA;
          *(ushort*)(tbuf + row * 160 + col * 2) = f2h(xacc[mm][n][rA]);
        }
      }
    }
    __syncthreads();  // transpose visible
    // coalesced store: 4 iters x 32 rows x 128B
    {
      const long dbase = (long)dirq * (B_ * T_);
#pragma unroll
      for (int it = 0; it < 4; ++it) {
        const int rowb = it * 32 + (tid >> 3);
        const int colb = (tid & 7) * 16;
        uint4 v = *(const uint4*)(tbuf + rowb * 160 + colb);
        *(uint4*)((char*)xgP + (dbase + m0 + rowb) * 512 + g64 * 128 + colb) =
            v;
      }
    }
  }
}

// ---------------- LSTM scan (R12 structure, 8-deep xg prefetch) ------------
// 128 blocks (2 dir x 64 groups of 4 seqs), 4 waves. Lane (c=4r+s, q) owns
// unit 16w+4q+r; 1 unit/lane -> 8 trans-ops/wave-step. h exchange via LDS
// 144B-stride rows (conflict-free). Merged-rcp nonlin, pre-scaled weights.
union U2 { uint u; __half2 h2; };

#define LSTEP(J, XR)                                                           \
  do {                                                                         \
    const int t_ = t0ph + (J);                                                 \
    const int p_ = t_ & 1;                                                     \
    const uint2 cur = XR;                                                      \
    {                                                                          \
      int tp = t_ + 8;                                                         \
      tp = tp > T_ - 1 ? T_ - 1 : tp;                                          \
      const int ttp = dir ? (T_ - 1 - tp) : tp;                                \
      XR = *(const uint2*)(xgbase + (long)ttp * 512);                          \
    }                                                                          \
    f16x8 bh0, bh1;                                                            \
    {                                                                          \
      const char* hb = hx + p_ * 576 + s * 144;                                \
      bh0 = *(const f16x8*)(hb + q * 16);                                      \
      bh1 = *(const f16x8*)(hb + 64 + q * 16);                                 \
    }                                                                          \
    f32x4 acc[4];                                                              \
    _Pragma("unroll") for (int n = 0; n < 4; ++n) {                            \
      acc[n] = __builtin_amdgcn_mfma_f32_16x16x32_f16(afA[n], bh0,             \
                                                      (f32x4)(0.f), 0, 0, 0);  \
      acc[n] =                                                                 \
          __builtin_amdgcn_mfma_f32_16x16x32_f16(afB[n], bh1, acc[n], 0, 0, 0);\
    }                                                                          \
    float ge[4];                                                               \
    _Pragma("unroll") for (int e = 0; e < 4; ++e) {                            \
      float v01 = (r & 1) ? acc[1][e] : acc[0][e];                             \
      float v23 = (r & 1) ? acc[3][e] : acc[2][e];                             \
      ge[e] = (r & 2) ? v23 : v01;                                             \
    }                                                                          \
    U2 ua, ub;                                                                 \
    ua.u = cur.x;                                                              \
    ub.u = cur.y;                                                              \
    float2 xif = __half22float2(ua.h2);                                        \
    float2 xgo = __half22float2(ub.h2);                                        \
    float gi = ge[0] + xif.x, gf = ge[1] + xif.y;                              \
    float gg = ge[2] + xgo.x, go = ge[3] + xgo.y;                              \
    float Ei = __builtin_amdgcn_exp2f(gi);                                     \
    float Ef = __builtin_amdgcn_exp2f(gf);                                     \
    float Eg = __builtin_amdgcn_exp2f(gg);                                     \
    float Eo = __builtin_amdgcn_exp2f(go);                                     \
    float sf = __builtin_amdgcn_rcpf(1.f + Ef);                                \
    float den = __builtin_amdgcn_rcpf((1.f + Ei) * (1.f + Eg));                \
    cst = fmaf(sf, cst, (Eg - 1.f) * den);                                     \
    float Ec = __builtin_amdgcn_exp2f(SC_TANH * cst);                          \
    float hval = (Ec - 1.f) * __builtin_amdgcn_rcpf((1.f + Eo) * (1.f + Ec));  \
    const ushort hu = f2h(hval);                                               \
    *(ushort*)(hx + (1 - p_) * 576 + s * 144 + ub_) = hu;                      \
    {                                                                          \
      const int gt = dir ? (T_ - 1 - t_) : t_;                                 \
      houtp[(long)gt * 128] = hu;                                              \
    }                                                                          \
    asm volatile("s_waitcnt lgkmcnt(0)" ::: "memory");                         \
    __builtin_amdgcn_sched_barrier(0);                                         \
    __builtin_amdgcn_s_barrier();                                              \
    __builtin_amdgcn_sched_barrier(0);                                         \
  } while (0)

__global__ __launch_bounds__(256, 1) void lstm_seq_kernel(
    const ushort* __restrict__ whhP, const ushort* __restrict__ xgP,
    ushort* __restrict__ hout) {
  const int dir = blockIdx.x >> 6;
  const int bg = blockIdx.x & 63;
  const int tid = threadIdx.x;
  const int lane = tid & 63;
  const int w = tid >> 6;   // wave 0..3
  const int c = lane & 15;  // MFMA column
  const int q = lane >> 4;  // quarter
  const int s = c & 3;      // sequence within group (4 seqs)
  const int r = c >> 2;     // replica id = which unit this lane owns

  __shared__ __align__(16) char hx[2 * 576];
  for (int i = tid; i < 288; i += 256) ((uint*)hx)[i] = 0u;

  f16x8 afA[4], afB[4];
  {
    const ushort* base = whhP + (long)dir * 256 * 64;
#pragma unroll
    for (int n = 0; n < 4; ++n) {
      const ushort* rp = base + (64 * w + 16 * n + c) * 64 + q * 8;
      afA[n] = *(const f16x8*)rp;
      afB[n] = *(const f16x8*)(rp + 32);
    }
  }

  const int b = bg * 4 + s;
  const int u = 16 * w + 4 * q + r;
  const int ub_ = u * 2;
  const char* xgbase = (const char*)xgP + (((long)dir * B_ + b) * T_) * 512 +
                       w * 128 + q * 32 + r * 8;
  ushort* houtp = hout + (long)b * T_ * 128 + dir * 64 + u;

  float cst = 0.f;

  // 8-deep xg prefetch (8B/step/lane)
  uint2 x0, x1, x2, x3, x4, x5, x6, x7;
  {
    x0 = *(const uint2*)(xgbase + (long)(dir ? T_ - 1 : 0) * 512);
    x1 = *(const uint2*)(xgbase + (long)(dir ? T_ - 2 : 1) * 512);
    x2 = *(const uint2*)(xgbase + (long)(dir ? T_ - 3 : 2) * 512);
    x3 = *(const uint2*)(xgbase + (long)(dir ? T_ - 4 : 3) * 512);
    x4 = *(const uint2*)(xgbase + (long)(dir ? T_ - 5 : 4) * 512);
    x5 = *(const uint2*)(xgbase + (long)(dir ? T_ - 6 : 5) * 512);
    x6 = *(const uint2*)(xgbase + (long)(dir ? T_ - 7 : 6) * 512);
    x7 = *(const uint2*)(xgbase + (long)(dir ? T_ - 8 : 7) * 512);
  }
  __syncthreads();

  for (int ph = 0; ph < 64; ++ph) {
    const int t0ph = ph * 8;
    LSTEP(0, x0);
    LSTEP(1, x1);
    LSTEP(2, x2);
    LSTEP(3, x3);
    LSTEP(4, x4);
    LSTEP(5, x5);
    LSTEP(6, x6);
    LSTEP(7, x7);
  }
}

// ---------------- Attention pool + LayerNorm + FC (fp16 hio) ---------------
__global__ __launch_bounds__(256) void head_kernel(
    const ushort* __restrict__ hio, const float* __restrict__ attn_w,
    const float* __restrict__ attn_b, const float* __restrict__ ln_g,
    const float* __restrict__ ln_b, const float* __restrict__ fc_w,
    const float* __restrict__ fc_b, float* __restrict__ res) {
  const int b = blockIdx.x;
  const int tid = threadIdx.x;
  __shared__ __align__(16) float aw[128];
  __shared__ float l[T_];
  __shared__ float red[16];
  __shared__ float pp[2][128];
  __shared__ float normed[128];
  if (tid < 128) aw[tid] = attn_w[tid];
  __syncthreads();
  const float ab = attn_b[0];

  for (int t = tid; t < T_; t += 256) {
    const ushort* row = hio + ((long)b * T_ + t) * 128;
    float a = ab;
#pragma unroll
    for (int d = 0; d < 128; d += 8) {
      uint4 v = *(const uint4*)(row + d);
      float2 p0 = __half22float2(*(const __half2*)&v.x);
      float2 p1 = __half22float2(*(const __half2*)&v.y);
      float2 p2 = __half22float2(*(const __half2*)&v.z);
      float2 p3 = __half22float2(*(const __half2*)&v.w);
      a += p0.x * aw[d] + p0.y * aw[d + 1] + p1.x * aw[d + 2] +
           p1.y * aw[d + 3] + p2.x * aw[d + 4] + p2.y * aw[d + 5] +
           p3.x * aw[d + 6] + p3.y * aw[d + 7];
    }
    l[t] = a;
  }
  __syncthreads();

  float v0 = l[tid], v1 = l[tid + 256];
  float m = fmaxf(v0, v1);
#pragma unroll
  for (int off = 32; off >= 1; off >>= 1) m = fmaxf(m, __shfl_xor(m, off));
  if ((tid & 63) == 0) red[tid >> 6] = m;
  __syncthreads();
  m = fmaxf(fmaxf(red[0], red[1]), fmaxf(red[2], red[3]));
  float e0 = __expf(v0 - m), e1 = __expf(v1 - m);
  float ssum = e0 + e1;
#pragma unroll
  for (int off = 32; off >= 1; off >>= 1) ssum += __shfl_xor(ssum, off);
  if ((tid & 63) == 0) red[4 + (tid >> 6)] = ssum;
  __syncthreads();
  float inv = 1.f / (red[4] + red[5] + red[6] + red[7]);
  l[tid] = e0 * inv;
  l[tid + 256] = e1 * inv;
  __syncthreads();

  const int d = tid & 127, half = tid >> 7;
  float p = 0.f;
  for (int t = half * 256; t < half * 256 + 256; ++t)
    p += l[t] * h2f(hio[((long)b * T_ + t) * 128 + d]);
  pp[half][d] = p;
  __syncthreads();

  if (tid < 128) {
    float pv = pp[0][tid] + pp[1][tid];
    float s1 = pv, s2 = pv * pv;
#pragma unroll
    for (int off = 32; off >= 1; off >>= 1) {
      s1 += __shfl_xor(s1, off);
      s2 += __shfl_xor(s2, off);
    }
    if ((tid & 63) == 0) {
      red[8 + (tid >> 6) * 2] = s1;
      red[9 + (tid >> 6) * 2] = s2;
    }
  }
  __syncthreads();
  if (tid < 128) {
    float s1 = red[8] + red[10], s2 = red[9] + red[11];
    float mu = s1 * (1.f / 128.f);
    float var = s2 * (1.f / 128.f) - mu * mu;
    float rinv = rsqrtf(var + 1e-5f);
    float pv = pp[0][tid] + pp[1][tid];
    normed[tid] = (pv - mu) * rinv * ln_g[tid] + ln_b[tid];
  }
  __syncthreads();

  if (tid < 2) {
    float a = fc_b[tid];
    for (int d2 = 0; d2 < 128; ++d2) a += normed[d2] * fc_w[tid * 128 + d2];
    res[b * 2 + tid] = a;
  }
}

extern "C" void kernel_launch(void* const* d_in, const int* in_sizes, int n_in,
                              void* d_out, int out_size, void* d_ws,
                              size_t ws_size, hipStream_t stream) {
  const float* x = (const float*)d_in[0];
  const float* conv_w = (const float*)d_in[1];
  const float* conv_b = (const float*)d_in[2];
  const float* w_ih_f = (const float*)d_in[3];
  const float* w_hh_f = (const float*)d_in[4];
  const float* b_f = (const float*)d_in[5];
  const float* w_ih_b = (const float*)d_in[6];
  const float* w_hh_b = (const float*)d_in[7];
  const float* b_b = (const float*)d_in[8];
  const float* attn_w = (const float*)d_in[9];
  const float* attn_b = (const float*)d_in[10];
  const float* ln_g = (const float*)d_in[11];
  const float* ln_b = (const float*)d_in[12];
  const float* fc_w = (const float*)d_in[13];
  const float* fc_b = (const float*)d_in[14];
  float* res = (float*)d_out;

  // ws layout (~169 MiB):
  char* ws = (char*)d_ws;
  ushort* wbT = (ushort*)ws;                       // 294,912 B
  ushort* wP = (ushort*)(ws + 0x60000);            // 131,072 B (bf16, scaled)
  ushort* whhP = (ushort*)(ws + 0x80000);          // 65,536 B (fp16, scaled)
  float* biasP = (float*)(ws + 0x90000);           // 2,048 B (scaled)
  ushort* xgP = (ushort*)(ws + 0x100000);          // 134,217,728 B (fp16)
  ushort* hout = (ushort*)(ws + 0x100000 + 134217728);  // 33,554,432 B (fp16)

  pack_w_kernel<<<576, 256, 0, stream>>>(conv_w, wbT);
  pack_wiP_kernel<<<256, 256, 0, stream>>>(w_ih_f, w_ih_b, wP);
  pack_whhP_kernel<<<128, 256, 0, stream>>>(w_hh_f, w_hh_b, whhP);
  pack_biasP_kernel<<<2, 256, 0, stream>>>(b_f, b_b, biasP);
  conv_xg_kernel<<<B_ * (T_ / 128), 256, 0, stream>>>(x, wbT, conv_b, wP,
                                                      biasP, xgP);
  lstm_seq_kernel<<<128, 256, 0, stream>>>(whhP, xgP, hout);
  head_kernel<<<B_, 256, 0, stream>>>(hout, attn_w, attn_b, ln_g, ln_b, fc_w,
                                      fc_b, res);
}

// Round 17
// 302.658 us; speedup vs baseline: 1.0708x; 1.0708x over previous
//
#include <hip/hip_runtime.h>
#include <hip/hip_fp16.h>
#include <math.h>

typedef unsigned int uint;
typedef unsigned short ushort;

#define B_ 256
#define T_ 512
#define F_ 378
#define C_ 128
#define H_ 64
#define KPAD 1152   // 3 * 384

using f32x4 = __attribute__((ext_vector_type(4))) float;
using bf16x8 = __attribute__((ext_vector_type(8))) short;
using f16x8 = __attribute__((ext_vector_type(8))) _Float16;

__device__ __forceinline__ ushort f2bf(float f) {
  union { float f; uint u; } c; c.f = f;
  uint r = (c.u + 0x7fffu + ((c.u >> 16) & 1u)) >> 16;
  return (ushort)r;
}
__device__ __forceinline__ uint packbf2(float a, float b) {
  return (uint)f2bf(a) | (((uint)f2bf(b)) << 16);
}
__device__ __forceinline__ ushort f2h(float f) {
  __half h = __float2half(f);
  return *(ushort*)&h;
}
__device__ __forceinline__ float h2f(ushort u) {
  __half h;
  *(ushort*)&h = u;
  return __half2float(h);
}
#define SC_SIG -1.442695041f
#define SC_TANH 2.885390082f

// ---------------- pack conv w -> wbT[c][kk], kk = k*384+f, bf16 ------------
__global__ __launch_bounds__(256) void pack_w_kernel(
    const float* __restrict__ w, ushort* __restrict__ wbT) {
  int i = blockIdx.x * 256 + threadIdx.x;
  if (i >= C_ * KPAD) return;
  int c = i / KPAD, kk = i - c * KPAD;
  int k = kk / 384, f = kk - k * 384;
  float v = (f < F_) ? w[c * (F_ * 3) + f * 3 + k] : 0.f;
  wbT[i] = f2bf(v);
}

// ---- pack w_ih -> wP[dir][g''][128] bf16, PRE-SCALED (R12 g'' order) ------
__global__ __launch_bounds__(256) void pack_wiP_kernel(
    const float* __restrict__ wf, const float* __restrict__ wb,
    ushort* __restrict__ wP) {
  int i = blockIdx.x * 256 + threadIdx.x;  // 2*256*128 = 65536
  int dir = i >> 15, rem = i & 32767;
  int gp = rem >> 7, k = rem & 127;
  int e = gp & 3, n = (gp >> 2) & 3, q = (gp >> 4) & 3, w = gp >> 6;
  int u = 16 * w + 4 * q + n;
  const float* src = dir ? wb : wf;
  float scale = (e == 2) ? SC_TANH : SC_SIG;
  wP[i] = f2bf(src[(e * 64 + u) * 128 + k] * scale);
}

// ---- pack w_hh -> whhP[dir][r][64] FP16, PRE-SCALED (4-wave mapping) ------
__global__ __launch_bounds__(256) void pack_whhP_kernel(
    const float* __restrict__ wf, const float* __restrict__ wb,
    ushort* __restrict__ whhP) {
  int i = blockIdx.x * 256 + threadIdx.x;  // 2*256*64 = 32768
  if (i >= 32768) return;
  int dir = i >> 14, rem = i & 16383;
  int r = rem >> 6, k = rem & 63;
  int e = r & 3, q = (r >> 2) & 3, n = (r >> 4) & 3, w = r >> 6;
  int u = 16 * w + 4 * q + n;
  const float* src = dir ? wb : wf;
  float scale = (e == 2) ? SC_TANH : SC_SIG;
  whhP[i] = f2h(src[(e * 64 + u) * 64 + k] * scale);
}

// ---- pack bias -> biasP[dir][g''] fp32, same order+scale as wP ------------
__global__ __launch_bounds__(256) void pack_biasP_kernel(
    const float* __restrict__ bf, const float* __restrict__ bb,
    float* __restrict__ biasP) {
  int i = blockIdx.x * 256 + threadIdx.x;  // 512
  if (i >= 512) return;
  int dir = i >> 8, gp = i & 255;
  int e = gp & 3, n = (gp >> 2) & 3, q = (gp >> 4) & 3, w = gp >> 6;
  int u = 16 * w + 4 * q + n;
  const float* src = dir ? bb : bf;
  float scale = (e == 2) ? SC_TANH : SC_SIG;
  biasP[i] = src[e * 64 + u] * scale;
}

// ---------------- FUSED Conv1d + xg GEMM ----------------------------------
// Phase 1: conv via implicit GEMM -> y tile bf16 staged in bsb[0:32K).
// Phase 2: 8 chunks x {stage wP (xsb), MFMA (bias C-init), transpose ->
// bsb[32K:48K), store}. Transpose XOR key ((row>>2)&3)<<5: per write
// instruction the four lane-quarters (row += 4 each) land on DISJOINT bank
// octets (32q' bytes = 8q' words), 16 lanes/octet = 2-way = free.
__global__ __launch_bounds__(256, 2) void conv_xg_kernel(
    const float* __restrict__ x, const ushort* __restrict__ wbT,
    const float* __restrict__ bias, const ushort* __restrict__ wP,
    const float* __restrict__ biasP, ushort* __restrict__ xgP) {
  __shared__ __align__(16) char xsb[130 * 128];  // conv-A / wP chunk
  __shared__ __align__(16) char bsb[128 * 384];  // conv-B / y tile / tbuf
  const int tid = threadIdx.x;
  const int lane = tid & 63;
  const int wr = (tid >> 7) & 1;
  const int wc = (tid >> 6) & 1;
  const int w = tid >> 6;
  const int b = blockIdx.x >> 2;
  const int t0 = (blockIdx.x & 3) << 7;

  f32x4 acc[4][4];
#pragma unroll
  for (int m = 0; m < 4; ++m)
#pragma unroll
    for (int n = 0; n < 4; ++n) acc[m][n] = (f32x4)(0.f);

  for (int fs = 0; fs < 6; ++fs) {
    __syncthreads();
    {
      auto stage_a = [&](int r, int h) {
        const int t = t0 - 1 + r;
        const bool ok = (t >= 0) && (t < T_);
        const float* srow = x + ((long)b * T_ + (ok ? t : 0)) * F_;
        const int fb = fs * 64 + h * 32;
        char* dst = xsb + r * 128;
        const int sw = (r & 7) << 4;
        uint pk[16];
        if (ok && fb + 31 < F_) {
#pragma unroll
          for (int j = 0; j < 16; ++j) {
            float2 v = *(const float2*)(srow + fb + 2 * j);
            pk[j] = packbf2(v.x, v.y);
          }
        } else {
#pragma unroll
          for (int j = 0; j < 16; ++j) {
            const int f = fb + 2 * j;
            float a = (ok && f < F_) ? srow[f] : 0.f;
            float c2 = (ok && f + 1 < F_) ? srow[f + 1] : 0.f;
            pk[j] = packbf2(a, c2);
          }
        }
#pragma unroll
        for (int j = 0; j < 4; ++j) {
          uint4 p = {pk[4 * j], pk[4 * j + 1], pk[4 * j + 2], pk[4 * j + 3]};
          *(uint4*)(dst + ((h * 64 + j * 16) ^ sw)) = p;
        }
      };
      stage_a(tid >> 1, tid & 1);
      if (tid < 4) stage_a(128 + (tid >> 1), tid & 1);
    }
    {
      const int c = tid >> 1, h = tid & 1;
      const ushort* src = wbT + c * KPAD + fs * 64 + h * 32;
      char* drow = bsb + c * 384;
      const int sw = (c & 7) << 4;
#pragma unroll
      for (int k = 0; k < 3; ++k)
#pragma unroll
        for (int j = 0; j < 4; ++j) {
          uint4 v = *(const uint4*)(src + k * 384 + j * 8);
          *(uint4*)(drow + k * 128 + ((h * 64 + j * 16) ^ sw)) = v;
        }
    }
    __syncthreads();

#pragma unroll
    for (int k = 0; k < 3; ++k) {
#pragma unroll
      for (int s = 0; s < 2; ++s) {
        bf16x8 af[4], bfx[4];
        const int ksub = s * 64 + ((lane >> 4) << 4);
#pragma unroll
        for (int m = 0; m < 4; ++m) {
          const int rr = wr * 64 + m * 16 + (lane & 15) + k;
          af[m] = *(const bf16x8*)(xsb + rr * 128 + (ksub ^ ((rr & 7) << 4)));
        }
#pragma unroll
        for (int n = 0; n < 4; ++n) {
          const int c = wc * 64 + n * 16 + (lane & 15);
          bfx[n] =
              *(const bf16x8*)(bsb + c * 384 + k * 128 + (ksub ^ ((c & 7) << 4)));
        }
#pragma unroll
        for (int m = 0; m < 4; ++m)
#pragma unroll
          for (int n = 0; n < 4; ++n)
            acc[m][n] = __builtin_amdgcn_mfma_f32_16x16x32_bf16(
                af[m], bfx[n], acc[m][n], 0, 0, 0);
      }
    }
  }

  // conv epilogue: bias+ReLU -> y tile (bf16, swizzled 256B rows) in bsb
  __syncthreads();
  {
    float bc[4];
#pragma unroll
    for (int n = 0; n < 4; ++n) bc[n] = bias[wc * 64 + n * 16 + (lane & 15)];
#pragma unroll
    for (int m = 0; m < 4; ++m) {
#pragma unroll
      for (int n = 0; n < 4; ++n) {
        const int col = wc * 64 + n * 16 + (lane & 15);
#pragma unroll
        for (int r = 0; r < 4; ++r) {
          const int row = wr * 64 + m * 16 + ((lane >> 4) << 2) + r;
          float v = acc[m][n][r] + bc[n];
          v = v > 0.f ? v : 0.f;
          *(ushort*)(bsb + row * 256 + ((col * 2) ^ ((row & 7) << 4))) =
              f2bf(v);
        }
      }
    }
  }

  // ---- phase 2: xg chunks. xg[t][g''] = y @ wP^T + biasP, fp16 ----
  const long m0 = (long)b * T_ + t0;
  char* const tbuf = bsb + 32768;  // 16KB transpose buffer (disjoint)
#pragma unroll 1
  for (int ch = 0; ch < 8; ++ch) {
    const int dirq = ch >> 2;
    const int g64 = ch & 3;
    const int gbase = dirq * 256 + g64 * 64;
    __syncthreads();  // prev MFMA done reading xsb; prev store done (tbuf)
    // stage wP rows gbase..gbase+63 into xsb (256B/row, swizzled)
    {
      const int r = tid >> 2, h4 = tid & 3;
      const ushort* src = wP + (long)(gbase + r) * 128 + h4 * 32;
      char* drow = xsb + r * 256;
      const int sw = (r & 7) << 4;
#pragma unroll
      for (int j = 0; j < 4; ++j) {
        uint4 v = *(const uint4*)(src + 8 * j);
        *(uint4*)(drow + ((h4 * 64 + j * 16) ^ sw)) = v;
      }
    }
    __syncthreads();  // wP ready
    // GEMM: wave w owns m-tiles {2w, 2w+1}; 4 n-tiles; K=128 (4 ks)
    f32x4 xacc[2][4];
#pragma unroll
    for (int n = 0; n < 4; ++n) {
      const float bcv = biasP[gbase + n * 16 + (lane & 15)];
      xacc[0][n] = (f32x4)(bcv);
      xacc[1][n] = (f32x4)(bcv);
    }
#pragma unroll
    for (int ks = 0; ks < 4; ++ks) {
      const int ksub = ks * 64 + ((lane >> 4) << 4);
      bf16x8 af[2], bfx[4];
#pragma unroll
      for (int mm = 0; mm < 2; ++mm) {
        const int rr = (w * 2 + mm) * 16 + (lane & 15);
        af[mm] = *(const bf16x8*)(bsb + rr * 256 + (ksub ^ ((rr & 7) << 4)));
      }
#pragma unroll
      for (int n = 0; n < 4; ++n) {
        const int rb = n * 16 + (lane & 15);
        bfx[n] = *(const bf16x8*)(xsb + rb * 256 + (ksub ^ ((rb & 7) << 4)));
      }
#pragma unroll
      for (int mm = 0; mm < 2; ++mm)
#pragma unroll
        for (int n = 0; n < 4; ++n)
          xacc[mm][n] = __builtin_amdgcn_mfma_f32_16x16x32_bf16(
              af[mm], bfx[n], xacc[mm][n], 0, 0, 0);
    }
    // transpose into tbuf: [128 t][128B] fp16, quarter-octet XOR
    // ((row>>2)&3)<<5: per instruction the 4 lane-quarters write disjoint
    // bank octets (conflict-free); bijective within each row.
#pragma unroll
    for (int mm = 0; mm < 2; ++mm) {
#pragma unroll
      for (int n = 0; n < 4; ++n) {
        const int col = n * 16 + (lane & 15);
#pragma unroll
        for (int rA = 0; rA < 4; ++rA) {
          const int row = (w * 2 + mm) * 16 + ((lane >> 4) << 2) + rA;
          *(ushort*)(tbuf + row * 128 +
                     ((col * 2) ^ (((row >> 2) & 3) << 5))) =
              f2h(xacc[mm][n][rA]);
        }
      }
    }
    __syncthreads();  // transpose visible
    // coalesced store: 4 iters x 32 rows x 128B
    {
      const long dbase = (long)dirq * (B_ * T_);
#pragma unroll
      for (int it = 0; it < 4; ++it) {
        const int rowb = it * 32 + (tid >> 3);
        const int colb = (tid & 7) * 16;
        uint4 v = *(const uint4*)(tbuf + rowb * 128 +
                                  (colb ^ (((rowb >> 2) & 3) << 5)));
        *(uint4*)((char*)xgP + (dbase + m0 + rowb) * 512 + g64 * 128 + colb) =
            v;
      }
    }
  }
}

// ---------------- LSTM scan (R12 structure, 8-deep xg prefetch) ------------
// 128 blocks (2 dir x 64 groups of 4 seqs), 4 waves. Lane (c=4r+s, q) owns
// unit 16w+4q+r; 1 unit/lane -> 8 trans-ops/wave-step. h exchange via LDS
// 144B-stride rows (conflict-free). Merged-rcp nonlin, pre-scaled weights.
union U2 { uint u; __half2 h2; };

#define LSTEP(J, XR)                                                           \
  do {                                                                         \
    const int t_ = t0ph + (J);                                                 \
    const int p_ = t_ & 1;                                                     \
    const uint2 cur = XR;                                                      \
    {                                                                          \
      int tp = t_ + 8;                                                         \
      tp = tp > T_ - 1 ? T_ - 1 : tp;                                          \
      const int ttp = dir ? (T_ - 1 - tp) : tp;                                \
      XR = *(const uint2*)(xgbase + (long)ttp * 512);                          \
    }                                                                          \
    f16x8 bh0, bh1;                                                            \
    {                                                                          \
      const char* hb = hx + p_ * 576 + s * 144;                                \
      bh0 = *(const f16x8*)(hb + q * 16);                                      \
      bh1 = *(const f16x8*)(hb + 64 + q * 16);                                 \
    }                                                                          \
    f32x4 acc[4];                                                              \
    _Pragma("unroll") for (int n = 0; n < 4; ++n) {                            \
      acc[n] = __builtin_amdgcn_mfma_f32_16x16x32_f16(afA[n], bh0,             \
                                                      (f32x4)(0.f), 0, 0, 0);  \
      acc[n] =                                                                 \
          __builtin_amdgcn_mfma_f32_16x16x32_f16(afB[n], bh1, acc[n], 0, 0, 0);\
    }                                                                          \
    float ge[4];                                                               \
    _Pragma("unroll") for (int e = 0; e < 4; ++e) {                            \
      float v01 = (r & 1) ? acc[1][e] : acc[0][e];                             \
      float v23 = (r & 1) ? acc[3][e] : acc[2][e];                             \
      ge[e] = (r & 2) ? v23 : v01;                                             \
    }                                                                          \
    U2 ua, ub;                                                                 \
    ua.u = cur.x;                                                              \
    ub.u = cur.y;                                                              \
    float2 xif = __half22float2(ua.h2);                                        \
    float2 xgo = __half22float2(ub.h2);                                        \
    float gi = ge[0] + xif.x, gf = ge[1] + xif.y;                              \
    float gg = ge[2] + xgo.x, go = ge[3] + xgo.y;                              \
    float Ei = __builtin_amdgcn_exp2f(gi);                                     \
    float Ef = __builtin_amdgcn_exp2f(gf);                                     \
    float Eg = __builtin_amdgcn_exp2f(gg);                                     \
    float Eo = __builtin_amdgcn_exp2f(go);                                     \
    float sf = __builtin_amdgcn_rcpf(1.f + Ef);                                \
    float den = __builtin_amdgcn_rcpf((1.f + Ei) * (1.f + Eg));                \
    cst = fmaf(sf, cst, (Eg - 1.f) * den);                                     \
    float Ec = __builtin_amdgcn_exp2f(SC_TANH * cst);                          \
    float hval = (Ec - 1.f) * __builtin_amdgcn_rcpf((1.f + Eo) * (1.f + Ec));  \
    const ushort hu = f2h(hval);                                               \
    *(ushort*)(hx + (1 - p_) * 576 + s * 144 + ub_) = hu;                      \
    {                                                                          \
      const int gt = dir ? (T_ - 1 - t_) : t_;                                 \
      houtp[(long)gt * 128] = hu;                                              \
    }                                                                          \
    asm volatile("s_waitcnt lgkmcnt(0)" ::: "memory");                         \
    __builtin_amdgcn_sched_barrier(0);                                         \
    __builtin_amdgcn_s_barrier();                                              \
    __builtin_amdgcn_sched_barrier(0);                                         \
  } while (0)

__global__ __launch_bounds__(256, 1) void lstm_seq_kernel(
    const ushort* __restrict__ whhP, const ushort* __restrict__ xgP,
    ushort* __restrict__ hout) {
  const int dir = blockIdx.x >> 6;
  const int bg = blockIdx.x & 63;
  const int tid = threadIdx.x;
  const int lane = tid & 63;
  const int w = tid >> 6;   // wave 0..3
  const int c = lane & 15;  // MFMA column
  const int q = lane >> 4;  // quarter
  const int s = c & 3;      // sequence within group (4 seqs)
  const int r = c >> 2;     // replica id = which unit this lane owns

  __shared__ __align__(16) char hx[2 * 576];
  for (int i = tid; i < 288; i += 256) ((uint*)hx)[i] = 0u;

  f16x8 afA[4], afB[4];
  {
    const ushort* base = whhP + (long)dir * 256 * 64;
#pragma unroll
    for (int n = 0; n < 4; ++n) {
      const ushort* rp = base + (64 * w + 16 * n + c) * 64 + q * 8;
      afA[n] = *(const f16x8*)rp;
      afB[n] = *(const f16x8*)(rp + 32);
    }
  }

  const int b = bg * 4 + s;
  const int u = 16 * w + 4 * q + r;
  const int ub_ = u * 2;
  const char* xgbase = (const char*)xgP + (((long)dir * B_ + b) * T_) * 512 +
                       w * 128 + q * 32 + r * 8;
  ushort* houtp = hout + (long)b * T_ * 128 + dir * 64 + u;

  float cst = 0.f;

  // 8-deep xg prefetch (8B/step/lane)
  uint2 x0, x1, x2, x3, x4, x5, x6, x7;
  {
    x0 = *(const uint2*)(xgbase + (long)(dir ? T_ - 1 : 0) * 512);
    x1 = *(const uint2*)(xgbase + (long)(dir ? T_ - 2 : 1) * 512);
    x2 = *(const uint2*)(xgbase + (long)(dir ? T_ - 3 : 2) * 512);
    x3 = *(const uint2*)(xgbase + (long)(dir ? T_ - 4 : 3) * 512);
    x4 = *(const uint2*)(xgbase + (long)(dir ? T_ - 5 : 4) * 512);
    x5 = *(const uint2*)(xgbase + (long)(dir ? T_ - 6 : 5) * 512);
    x6 = *(const uint2*)(xgbase + (long)(dir ? T_ - 7 : 6) * 512);
    x7 = *(const uint2*)(xgbase + (long)(dir ? T_ - 8 : 7) * 512);
  }
  __syncthreads();

  for (int ph = 0; ph < 64; ++ph) {
    const int t0ph = ph * 8;
    LSTEP(0, x0);
    LSTEP(1, x1);
    LSTEP(2, x2);
    LSTEP(3, x3);
    LSTEP(4, x4);
    LSTEP(5, x5);
    LSTEP(6, x6);
    LSTEP(7, x7);
  }
}

// ---------------- Attention pool + LayerNorm + FC (fp16 hio) ---------------
__global__ __launch_bounds__(256) void head_kernel(
    const ushort* __restrict__ hio, const float* __restrict__ attn_w,
    const float* __restrict__ attn_b, const float* __restrict__ ln_g,
    const float* __restrict__ ln_b, const float* __restrict__ fc_w,
    const float* __restrict__ fc_b, float* __restrict__ res) {
  const int b = blockIdx.x;
  const int tid = threadIdx.x;
  __shared__ __align__(16) float aw[128];
  __shared__ float l[T_];
  __shared__ float red[16];
  __shared__ float pp[2][128];
  __shared__ float normed[128];
  if (tid < 128) aw[tid] = attn_w[tid];
  __syncthreads();
  const float ab = attn_b[0];

  for (int t = tid; t < T_; t += 256) {
    const ushort* row = hio + ((long)b * T_ + t) * 128;
    float a = ab;
#pragma unroll
    for (int d = 0; d < 128; d += 8) {
      uint4 v = *(const uint4*)(row + d);
      float2 p0 = __half22float2(*(const __half2*)&v.x);
      float2 p1 = __half22float2(*(const __half2*)&v.y);
      float2 p2 = __half22float2(*(const __half2*)&v.z);
      float2 p3 = __half22float2(*(const __half2*)&v.w);
      a += p0.x * aw[d] + p0.y * aw[d + 1] + p1.x * aw[d + 2] +
           p1.y * aw[d + 3] + p2.x * aw[d + 4] + p2.y * aw[d + 5] +
           p3.x * aw[d + 6] + p3.y * aw[d + 7];
    }
    l[t] = a;
  }
  __syncthreads();

  float v0 = l[tid], v1 = l[tid + 256];
  float m = fmaxf(v0, v1);
#pragma unroll
  for (int off = 32; off >= 1; off >>= 1) m = fmaxf(m, __shfl_xor(m, off));
  if ((tid & 63) == 0) red[tid >> 6] = m;
  __syncthreads();
  m = fmaxf(fmaxf(red[0], red[1]), fmaxf(red[2], red[3]));
  float e0 = __expf(v0 - m), e1 = __expf(v1 - m);
  float ssum = e0 + e1;
#pragma unroll
  for (int off = 32; off >= 1; off >>= 1) ssum += __shfl_xor(ssum, off);
  if ((tid & 63) == 0) red[4 + (tid >> 6)] = ssum;
  __syncthreads();
  float inv = 1.f / (red[4] + red[5] + red[6] + red[7]);
  l[tid] = e0 * inv;
  l[tid + 256] = e1 * inv;
  __syncthreads();

  const int d = tid & 127, half = tid >> 7;
  float p = 0.f;
  for (int t = half * 256; t < half * 256 + 256; ++t)
    p += l[t] * h2f(hio[((long)b * T_ + t) * 128 + d]);
  pp[half][d] = p;
  __syncthreads();

  if (tid < 128) {
    float pv = pp[0][tid] + pp[1][tid];
    float s1 = pv, s2 = pv * pv;
#pragma unroll
    for (int off = 32; off >= 1; off >>= 1) {
      s1 += __shfl_xor(s1, off);
      s2 += __shfl_xor(s2, off);
    }
    if ((tid & 63) == 0) {
      red[8 + (tid >> 6) * 2] = s1;
      red[9 + (tid >> 6) * 2] = s2;
    }
  }
  __syncthreads();
  if (tid < 128) {
    float s1 = red[8] + red[10], s2 = red[9] + red[11];
    float mu = s1 * (1.f / 128.f);
    float var = s2 * (1.f / 128.f) - mu * mu;
    float rinv = rsqrtf(var + 1e-5f);
    float pv = pp[0][tid] + pp[1][tid];
    normed[tid] = (pv - mu) * rinv * ln_g[tid] + ln_b[tid];
  }
  __syncthreads();

  if (tid < 2) {
    float a = fc_b[tid];
    for (int d2 = 0; d2 < 128; ++d2) a += normed[d2] * fc_w[tid * 128 + d2];
    res[b * 2 + tid] = a;
  }
}

extern "C" void kernel_launch(void* const* d_in, const int* in_sizes, int n_in,
                              void* d_out, int out_size, void* d_ws,
                              size_t ws_size, hipStream_t stream) {
  const float* x = (const float*)d_in[0];
  const float* conv_w = (const float*)d_in[1];
  const float* conv_b = (const float*)d_in[2];
  const float* w_ih_f = (const float*)d_in[3];
  const float* w_hh_f = (const float*)d_in[4];
  const float* b_f = (const float*)d_in[5];
  const float* w_ih_b = (const float*)d_in[6];
  const float* w_hh_b = (const float*)d_in[7];
  const float* b_b = (const float*)d_in[8];
  const float* attn_w = (const float*)d_in[9];
  const float* attn_b = (const float*)d_in[10];
  const float* ln_g = (const float*)d_in[11];
  const float* ln_b = (const float*)d_in[12];
  const float* fc_w = (const float*)d_in[13];
  const float* fc_b = (const float*)d_in[14];
  float* res = (float*)d_out;

  // ws layout (~169 MiB):
  char* ws = (char*)d_ws;
  ushort* wbT = (ushort*)ws;                       // 294,912 B
  ushort* wP = (ushort*)(ws + 0x60000);            // 131,072 B (bf16, scaled)
  ushort* whhP = (ushort*)(ws + 0x80000);          // 65,536 B (fp16, scaled)
  float* biasP = (float*)(ws + 0x90000);           // 2,048 B (scaled)
  ushort* xgP = (ushort*)(ws + 0x100000);          // 134,217,728 B (fp16)
  ushort* hout = (ushort*)(ws + 0x100000 + 134217728);  // 33,554,432 B (fp16)

  pack_w_kernel<<<576, 256, 0, stream>>>(conv_w, wbT);
  pack_wiP_kernel<<<256, 256, 0, stream>>>(w_ih_f, w_ih_b, wP);
  pack_whhP_kernel<<<128, 256, 0, stream>>>(w_hh_f, w_hh_b, whhP);
  pack_biasP_kernel<<<2, 256, 0, stream>>>(b_f, b_b, biasP);
  conv_xg_kernel<<<B_ * (T_ / 128), 256, 0, stream>>>(x, wbT, conv_b, wP,
                                                      biasP, xgP);
  lstm_seq_kernel<<<128, 256, 0, stream>>>(whhP, xgP, hout);
  head_kernel<<<B_, 256, 0, stream>>>(hout, attn_w, attn_b, ln_g, ln_b, fc_w,
                                      fc_b, res);
}

// Round 18
// 297.279 us; speedup vs baseline: 1.0902x; 1.0181x over previous
//
#include <hip/hip_runtime.h>
#include <hip/hip_fp16.h>
#include <math.h>

typedef unsigned int uint;
typedef unsigned short ushort;

#define B_ 256
#define T_ 512
#define F_ 378
#define C_ 128
#define H_ 64
#define KPAD 1152   // 3 * 384

using f32x4 = __attribute__((ext_vector_type(4))) float;
using bf16x8 = __attribute__((ext_vector_type(8))) short;
using f16x8 = __attribute__((ext_vector_type(8))) _Float16;

__device__ __forceinline__ ushort f2bf(float f) {
  union { float f; uint u; } c; c.f = f;
  uint r = (c.u + 0x7fffu + ((c.u >> 16) & 1u)) >> 16;
  return (ushort)r;
}
__device__ __forceinline__ uint packbf2(float a, float b) {
  return (uint)f2bf(a) | (((uint)f2bf(b)) << 16);
}
__device__ __forceinline__ ushort f2h(float f) {
  __half h = __float2half(f);
  return *(ushort*)&h;
}
__device__ __forceinline__ float h2f(ushort u) {
  __half h;
  *(ushort*)&h = u;
  return __half2float(h);
}
#define SC_SIG -1.442695041f
#define SC_TANH 2.885390082f

// ---------------- pack conv w -> wbT[c][kk], kk = k*384+f, bf16 ------------
__global__ __launch_bounds__(256) void pack_w_kernel(
    const float* __restrict__ w, ushort* __restrict__ wbT) {
  int i = blockIdx.x * 256 + threadIdx.x;
  if (i >= C_ * KPAD) return;
  int c = i / KPAD, kk = i - c * KPAD;
  int k = kk / 384, f = kk - k * 384;
  float v = (f < F_) ? w[c * (F_ * 3) + f * 3 + k] : 0.f;
  wbT[i] = f2bf(v);
}

// ---- pack w_ih -> wP[dir][g''][128] bf16, PRE-SCALED (R12 g'' order) ------
// g'' = w*64 + q*16 + n*4 + e -> orig gate row e*64 + (16w + 4q + n).
__global__ __launch_bounds__(256) void pack_wiP_kernel(
    const float* __restrict__ wf, const float* __restrict__ wb,
    ushort* __restrict__ wP) {
  int i = blockIdx.x * 256 + threadIdx.x;  // 2*256*128 = 65536
  int dir = i >> 15, rem = i & 32767;
  int gp = rem >> 7, k = rem & 127;
  int e = gp & 3, n = (gp >> 2) & 3, q = (gp >> 4) & 3, w = gp >> 6;
  int u = 16 * w + 4 * q + n;
  const float* src = dir ? wb : wf;
  float scale = (e == 2) ? SC_TANH : SC_SIG;
  wP[i] = f2bf(src[(e * 64 + u) * 128 + k] * scale);
}

// ---- pack w_hh -> whhP[dir][r][64] FP16, PRE-SCALED (4-wave mapping) ------
__global__ __launch_bounds__(256) void pack_whhP_kernel(
    const float* __restrict__ wf, const float* __restrict__ wb,
    ushort* __restrict__ whhP) {
  int i = blockIdx.x * 256 + threadIdx.x;  // 2*256*64 = 32768
  if (i >= 32768) return;
  int dir = i >> 14, rem = i & 16383;
  int r = rem >> 6, k = rem & 63;
  int e = r & 3, q = (r >> 2) & 3, n = (r >> 4) & 3, w = r >> 6;
  int u = 16 * w + 4 * q + n;
  const float* src = dir ? wb : wf;
  float scale = (e == 2) ? SC_TANH : SC_SIG;
  whhP[i] = f2h(src[(e * 64 + u) * 64 + k] * scale);
}

// ---- pack bias -> biasP[dir][g''] fp32, same order+scale as wP ------------
__global__ __launch_bounds__(256) void pack_biasP_kernel(
    const float* __restrict__ bf, const float* __restrict__ bb,
    float* __restrict__ biasP) {
  int i = blockIdx.x * 256 + threadIdx.x;  // 512
  if (i >= 512) return;
  int dir = i >> 8, gp = i & 255;
  int e = gp & 3, n = (gp >> 2) & 3, q = (gp >> 4) & 3, w = gp >> 6;
  int u = 16 * w + 4 * q + n;
  const float* src = dir ? bb : bf;
  float scale = (e == 2) ? SC_TANH : SC_SIG;
  biasP[i] = src[e * 64 + u] * scale;
}

// ---------------- Conv1d as implicit GEMM, bf16 MFMA (R12 version) ---------
// Writes y[b*T+t][128c] bf16 (coalesced). No xg phase (xg is produced in the
// scan by dedicated producer waves -> 268MB of xgP HBM traffic deleted).
__global__ __launch_bounds__(256, 2) void conv_gemm_kernel(
    const float* __restrict__ x, const ushort* __restrict__ wbT,
    const float* __restrict__ bias, ushort* __restrict__ y) {
  __shared__ __align__(16) char xsb[130 * 128];
  __shared__ __align__(16) char bsb[128 * 384];
  const int tid = threadIdx.x;
  const int lane = tid & 63;
  const int wr = (tid >> 7) & 1;
  const int wc = (tid >> 6) & 1;
  const int b = blockIdx.x >> 2;
  const int t0 = (blockIdx.x & 3) << 7;

  f32x4 acc[4][4];
#pragma unroll
  for (int m = 0; m < 4; ++m)
#pragma unroll
    for (int n = 0; n < 4; ++n) acc[m][n] = (f32x4)(0.f);

  for (int fs = 0; fs < 6; ++fs) {
    __syncthreads();
    {
      auto stage_a = [&](int r, int h) {
        const int t = t0 - 1 + r;
        const bool ok = (t >= 0) && (t < T_);
        const float* srow = x + ((long)b * T_ + (ok ? t : 0)) * F_;
        const int fb = fs * 64 + h * 32;
        char* dst = xsb + r * 128;
        const int sw = (r & 7) << 4;
        uint pk[16];
        if (ok && fb + 31 < F_) {
#pragma unroll
          for (int j = 0; j < 16; ++j) {
            float2 v = *(const float2*)(srow + fb + 2 * j);
            pk[j] = packbf2(v.x, v.y);
          }
        } else {
#pragma unroll
          for (int j = 0; j < 16; ++j) {
            const int f = fb + 2 * j;
            float a = (ok && f < F_) ? srow[f] : 0.f;
            float c2 = (ok && f + 1 < F_) ? srow[f + 1] : 0.f;
            pk[j] = packbf2(a, c2);
          }
        }
#pragma unroll
        for (int j = 0; j < 4; ++j) {
          uint4 p = {pk[4 * j], pk[4 * j + 1], pk[4 * j + 2], pk[4 * j + 3]};
          *(uint4*)(dst + ((h * 64 + j * 16) ^ sw)) = p;
        }
      };
      stage_a(tid >> 1, tid & 1);
      if (tid < 4) stage_a(128 + (tid >> 1), tid & 1);
    }
    {
      const int c = tid >> 1, h = tid & 1;
      const ushort* src = wbT + c * KPAD + fs * 64 + h * 32;
      char* drow = bsb + c * 384;
      const int sw = (c & 7) << 4;
#pragma unroll
      for (int k = 0; k < 3; ++k)
#pragma unroll
        for (int j = 0; j < 4; ++j) {
          uint4 v = *(const uint4*)(src + k * 384 + j * 8);
          *(uint4*)(drow + k * 128 + ((h * 64 + j * 16) ^ sw)) = v;
        }
    }
    __syncthreads();

#pragma unroll
    for (int k = 0; k < 3; ++k) {
#pragma unroll
      for (int s = 0; s < 2; ++s) {
        bf16x8 af[4], bfx[4];
        const int ksub = s * 64 + ((lane >> 4) << 4);
#pragma unroll
        for (int m = 0; m < 4; ++m) {
          const int rr = wr * 64 + m * 16 + (lane & 15) + k;
          af[m] = *(const bf16x8*)(xsb + rr * 128 + (ksub ^ ((rr & 7) << 4)));
        }
#pragma unroll
        for (int n = 0; n < 4; ++n) {
          const int c = wc * 64 + n * 16 + (lane & 15);
          bfx[n] =
              *(const bf16x8*)(bsb + c * 384 + k * 128 + (ksub ^ ((c & 7) << 4)));
        }
#pragma unroll
        for (int m = 0; m < 4; ++m)
#pragma unroll
          for (int n = 0; n < 4; ++n)
            acc[m][n] = __builtin_amdgcn_mfma_f32_16x16x32_bf16(
                af[m], bfx[n], acc[m][n], 0, 0, 0);
      }
    }
  }

  __syncthreads();
  float bc[4];
#pragma unroll
  for (int n = 0; n < 4; ++n) bc[n] = bias[wc * 64 + n * 16 + (lane & 15)];
#pragma unroll
  for (int m = 0; m < 4; ++m) {
#pragma unroll
    for (int n = 0; n < 4; ++n) {
      const int col = wc * 64 + n * 16 + (lane & 15);
#pragma unroll
      for (int r = 0; r < 4; ++r) {
        const int row = wr * 64 + m * 16 + ((lane >> 4) << 2) + r;
        float v = acc[m][n][r] + bc[n];
        v = v > 0.f ? v : 0.f;
        *(ushort*)(bsb + row * 256 + ((col * 2) ^ ((row & 7) << 4))) = f2bf(v);
      }
    }
  }
  __syncthreads();
  const int w = tid >> 6;
#pragma unroll
  for (int p = 0; p < 8; ++p) {
    const int rowb = p * 16 + w * 4 + (lane >> 4);
    const int colb = (lane & 15) * 16;
    uint4 v = *(const uint4*)(bsb + rowb * 256 + (colb ^ ((rowb & 7) << 4)));
    *(uint4*)((char*)(y + ((long)b * T_ + t0 + rowb) * 128) + colb) = v;
  }
}

// ---------------- LSTM scan: producer-consumer wave specialization ---------
// 128 blocks (2 dir x 64 groups of 4 seqs), 8 waves. Waves 0-3 = R12-style
// consumer scan (replica-spread nonlin, 740cy/step critical path untouched).
// Waves 4-7 = producers: xg[t][256g''] = wP @ y + bias via MFMA, 4 timesteps
// per round, 8 steps ahead of the consumer, into a 16-slot LDS ring. m114:
// separate waves co-schedule (time ~ max) -- producer issue hides in the
// consumer's chain-stall, unlike R13's same-wave fusion. Barrier counts
// match exactly (4 per ph on both paths). Ring separation: writer at t+8,
// reader at t, 16 slots -> never collide.
union U2 { uint u; __half2 h2; };

#define CSTEP(J)                                                               \
  do {                                                                         \
    const int t_ = t0ph + (J);                                                 \
    const int p_ = t_ & 1;                                                     \
    const int slot_ = ((ph & 3) << 2) + (J);                                   \
    const uint2 cur = *(const uint2*)(xgL + slot_ * 2176 + cOffL);             \
    f16x8 bh0, bh1;                                                            \
    {                                                                          \
      const char* hb = hx + p_ * 576 + s * 144;                                \
      bh0 = *(const f16x8*)(hb + q * 16);                                      \
      bh1 = *(const f16x8*)(hb + 64 + q * 16);                                 \
    }                                                                          \
    f32x4 acc[4];                                                              \
    _Pragma("unroll") for (int n = 0; n < 4; ++n) {                            \
      acc[n] = __builtin_amdgcn_mfma_f32_16x16x32_f16(afA[n], bh0,             \
                                                      (f32x4)(0.f), 0, 0, 0);  \
      acc[n] =                                                                 \
          __builtin_amdgcn_mfma_f32_16x16x32_f16(afB[n], bh1, acc[n], 0, 0, 0);\
    }                                                                          \
    float ge[4];                                                               \
    _Pragma("unroll") for (int e = 0; e < 4; ++e) {                            \
      float v01 = (r & 1) ? acc[1][e] : acc[0][e];                             \
      float v23 = (r & 1) ? acc[3][e] : acc[2][e];                             \
      ge[e] = (r & 2) ? v23 : v01;                                             \
    }                                                                          \
    U2 ua, ub;                                                                 \
    ua.u = cur.x;                                                              \
    ub.u = cur.y;                                                              \
    float2 xif = __half22float2(ua.h2);                                        \
    float2 xgo = __half22float2(ub.h2);                                        \
    float gi = ge[0] + xif.x, gf = ge[1] + xif.y;                              \
    float gg = ge[2] + xgo.x, go = ge[3] + xgo.y;                              \
    float Ei = __builtin_amdgcn_exp2f(gi);                                     \
    float Ef = __builtin_amdgcn_exp2f(gf);                                     \
    float Eg = __builtin_amdgcn_exp2f(gg);                                     \
    float Eo = __builtin_amdgcn_exp2f(go);                                     \
    float sf = __builtin_amdgcn_rcpf(1.f + Ef);                                \
    float den = __builtin_amdgcn_rcpf((1.f + Ei) * (1.f + Eg));                \
    cst = fmaf(sf, cst, (Eg - 1.f) * den);                                     \
    float Ec = __builtin_amdgcn_exp2f(SC_TANH * cst);                          \
    float hval = (Ec - 1.f) * __builtin_amdgcn_rcpf((1.f + Eo) * (1.f + Ec));  \
    const ushort hu = f2h(hval);                                               \
    *(ushort*)(hx + (1 - p_) * 576 + s * 144 + ub_) = hu;                      \
    {                                                                          \
      const int gt = dir ? (T_ - 1 - t_) : t_;                                 \
      houtp[(long)gt * 128] = hu;                                              \
    }                                                                          \
    asm volatile("s_waitcnt lgkmcnt(0)" ::: "memory");                         \
    __builtin_amdgcn_sched_barrier(0);                                         \
    __builtin_amdgcn_s_barrier();                                              \
    __builtin_amdgcn_sched_barrier(0);                                         \
  } while (0)

// Producer round: compute xg for timesteps TP0..TP0+3 (lane col = 4*toff+sP)
// using YF (preloaded), then reload YF for TP0+8. D-frag lane (col, qp),
// acc[n] elems e -> g'' = 64pw+16n+4qp+e == consumer (w=pw,q=n,r=qp) 8B read.
#define PROUND(TP0, YF)                                                        \
  do {                                                                         \
    f32x4 pacc[4];                                                             \
    _Pragma("unroll") for (int n = 0; n < 4; ++n) pacc[n] = biasC[n];          \
    _Pragma("unroll") for (int kk = 0; kk < 4; ++kk) {                         \
      _Pragma("unroll") for (int n = 0; n < 4; ++n)                            \
        pacc[n] = __builtin_amdgcn_mfma_f32_16x16x32_bf16(wiA[n][kk], YF[kk],  \
                                                          pacc[n], 0, 0, 0);   \
    }                                                                          \
    {                                                                          \
      int tt = (TP0) + 8 + toff;                                               \
      tt = tt > T_ - 1 ? T_ - 1 : tt;                                          \
      const int dt = dir ? (T_ - 1 - tt) : tt;                                 \
      const char* yr = ybaseP + (long)dt * 256;                                \
      _Pragma("unroll") for (int kk = 0; kk < 4; ++kk)                         \
        YF[kk] = *(const bf16x8*)(yr + kk * 64 + qp * 16);                     \
    }                                                                          \
    {                                                                          \
      const int slot_ = ((TP0) + toff) & 15;                                   \
      char* wp_ = xgL + slot_ * 2176 + sP * 544 + 128 * pw + 8 * qp;           \
      _Pragma("unroll") for (int n = 0; n < 4; ++n) {                          \
        uint2 hv;                                                              \
        hv.x = (uint)f2h(pacc[n][0]) | ((uint)f2h(pacc[n][1]) << 16);          \
        hv.y = (uint)f2h(pacc[n][2]) | ((uint)f2h(pacc[n][3]) << 16);          \
        *(uint2*)(wp_ + 32 * n) = hv;                                          \
      }                                                                        \
    }                                                                          \
  } while (0)

#define PBAR                                                                   \
  do {                                                                         \
    asm volatile("s_waitcnt lgkmcnt(0)" ::: "memory");                         \
    __builtin_amdgcn_sched_barrier(0);                                         \
    __builtin_amdgcn_s_barrier();                                              \
    __builtin_amdgcn_sched_barrier(0);                                         \
  } while (0)

__global__ __launch_bounds__(512, 1) void lstm_seq_kernel(
    const ushort* __restrict__ whhP, const ushort* __restrict__ wP,
    const float* __restrict__ biasP, const ushort* __restrict__ y,
    ushort* __restrict__ hout) {
  const int dir = blockIdx.x >> 6;
  const int bg = blockIdx.x & 63;
  const int tid = threadIdx.x;
  const int lane = tid & 63;
  const int wv = tid >> 6;  // 0..3 consumer, 4..7 producer

  // xg ring: 16 slots x [4 s(544B) -> 256 g'' fp16]; hx: h exchange
  __shared__ __align__(16) char xgL[16 * 2176];  // 34816 B
  __shared__ __align__(16) char hx[2 * 576];
  for (int i = tid; i < 288; i += 512) ((uint*)hx)[i] = 0u;

  if (wv < 4) {
    // ---------------- consumer ----------------
    const int w = wv;
    const int c = lane & 15;
    const int q = lane >> 4;
    const int s = c & 3;
    const int r = c >> 2;

    f16x8 afA[4], afB[4];
    {
      const ushort* base = whhP + (long)dir * 256 * 64;
#pragma unroll
      for (int n = 0; n < 4; ++n) {
        const ushort* rp = base + (64 * w + 16 * n + c) * 64 + q * 8;
        afA[n] = *(const f16x8*)rp;
        afB[n] = *(const f16x8*)(rp + 32);
      }
    }

    const int b = bg * 4 + s;
    const int u = 16 * w + 4 * q + r;
    const int ub_ = u * 2;
    const int cOffL = s * 544 + 128 * w + 32 * q + 8 * r;
    ushort* houtp = hout + (long)b * T_ * 128 + dir * 64 + u;

    float cst = 0.f;

    __syncthreads();  // producers filled slots 0..7

#pragma unroll 1
    for (int ph = 0; ph < 128; ++ph) {
      const int t0ph = ph * 4;
      CSTEP(0);
      CSTEP(1);
      CSTEP(2);
      CSTEP(3);
    }
  } else {
    // ---------------- producer ----------------
    const int pw = wv - 4;            // covers g'' block [64*pw, 64*pw+64)
    const int sP = lane & 3;          // sequence
    const int toff = (lane >> 2) & 3; // timestep offset within round
    const int qp = lane >> 4;         // row-quarter of D tile

    // pinned A-frags: wP rows 64pw+16n+(lane&15), K=128 in 4 chunks
    bf16x8 wiA[4][4];
    {
      const ushort* base2 = wP + (long)dir * 256 * 128;
#pragma unroll
      for (int n = 0; n < 4; ++n)
#pragma unroll
        for (int kk = 0; kk < 4; ++kk)
          wiA[n][kk] = *(const bf16x8*)(base2 +
                                        (64 * pw + 16 * n + (lane & 15)) * 128 +
                                        32 * kk + 8 * qp);
    }
    f32x4 biasC[4];
#pragma unroll
    for (int n = 0; n < 4; ++n)
      biasC[n] =
          *(const f32x4*)(biasP + dir * 256 + 64 * pw + 16 * n + 4 * qp);

    const int b = bg * 4 + sP;
    const char* ybaseP = (const char*)y + (long)b * T_ * 256 + 0;

    bf16x8 yfA[4], yfB[4];
    // prologue loads: t = 0..3 -> yfA, t = 4..7 -> yfB
    {
      int tt = 0 + toff;
      const int dt = dir ? (T_ - 1 - tt) : tt;
      const char* yr = ybaseP + (long)dt * 256;
#pragma unroll
      for (int kk = 0; kk < 4; ++kk)
        yfA[kk] = *(const bf16x8*)(yr + kk * 64 + qp * 16);
    }
    {
      int tt = 4 + toff;
      const int dt = dir ? (T_ - 1 - tt) : tt;
      const char* yr = ybaseP + (long)dt * 256;
#pragma unroll
      for (int kk = 0; kk < 4; ++kk)
        yfB[kk] = *(const bf16x8*)(yr + kk * 64 + qp * 16);
    }
    // prologue rounds: fill slots 0..7; reload yfA<-t8..11, yfB<-t12..15
    PROUND(0, yfA);
    PROUND(4, yfB);

    __syncthreads();  // consumers may start

#pragma unroll 1
    for (int ph = 0; ph < 128; ++ph) {
      const int tp0 = ph * 4 + 8;
      if ((ph & 1) == 0) {
        PROUND(tp0, yfA);
      } else {
        PROUND(tp0, yfB);
      }
      PBAR;
      PBAR;
      PBAR;
      PBAR;
    }
  }
}

// ---------------- Attention pool + LayerNorm + FC (fp16 hio) ---------------
__global__ __launch_bounds__(256) void head_kernel(
    const ushort* __restrict__ hio, const float* __restrict__ attn_w,
    const float* __restrict__ attn_b, const float* __restrict__ ln_g,
    const float* __restrict__ ln_b, const float* __restrict__ fc_w,
    const float* __restrict__ fc_b, float* __restrict__ res) {
  const int b = blockIdx.x;
  const int tid = threadIdx.x;
  __shared__ __align__(16) float aw[128];
  __shared__ float l[T_];
  __shared__ float red[16];
  __shared__ float pp[2][128];
  __shared__ float normed[128];
  if (tid < 128) aw[tid] = attn_w[tid];
  __syncthreads();
  const float ab = attn_b[0];

  for (int t = tid; t < T_; t += 256) {
    const ushort* row = hio + ((long)b * T_ + t) * 128;
    float a = ab;
#pragma unroll
    for (int d = 0; d < 128; d += 8) {
      uint4 v = *(const uint4*)(row + d);
      float2 p0 = __half22float2(*(const __half2*)&v.x);
      float2 p1 = __half22float2(*(const __half2*)&v.y);
      float2 p2 = __half22float2(*(const __half2*)&v.z);
      float2 p3 = __half22float2(*(const __half2*)&v.w);
      a += p0.x * aw[d] + p0.y * aw[d + 1] + p1.x * aw[d + 2] +
           p1.y * aw[d + 3] + p2.x * aw[d + 4] + p2.y * aw[d + 5] +
           p3.x * aw[d + 6] + p3.y * aw[d + 7];
    }
    l[t] = a;
  }
  __syncthreads();

  float v0 = l[tid], v1 = l[tid + 256];
  float m = fmaxf(v0, v1);
#pragma unroll
  for (int off = 32; off >= 1; off >>= 1) m = fmaxf(m, __shfl_xor(m, off));
  if ((tid & 63) == 0) red[tid >> 6] = m;
  __syncthreads();
  m = fmaxf(fmaxf(red[0], red[1]), fmaxf(red[2], red[3]));
  float e0 = __expf(v0 - m), e1 = __expf(v1 - m);
  float ssum = e0 + e1;
#pragma unroll
  for (int off = 32; off >= 1; off >>= 1) ssum += __shfl_xor(ssum, off);
  if ((tid & 63) == 0) red[4 + (tid >> 6)] = ssum;
  __syncthreads();
  float inv = 1.f / (red[4] + red[5] + red[6] + red[7]);
  l[tid] = e0 * inv;
  l[tid + 256] = e1 * inv;
  __syncthreads();

  const int d = tid & 127, half = tid >> 7;
  float p = 0.f;
  for (int t = half * 256; t < half * 256 + 256; ++t)
    p += l[t] * h2f(hio[((long)b * T_ + t) * 128 + d]);
  pp[half][d] = p;
  __syncthreads();

  if (tid < 128) {
    float pv = pp[0][tid] + pp[1][tid];
    float s1 = pv, s2 = pv * pv;
#pragma unroll
    for (int off = 32; off >= 1; off >>= 1) {
      s1 += __shfl_xor(s1, off);
      s2 += __shfl_xor(s2, off);
    }
    if ((tid & 63) == 0) {
      red[8 + (tid >> 6) * 2] = s1;
      red[9 + (tid >> 6) * 2] = s2;
    }
  }
  __syncthreads();
  if (tid < 128) {
    float s1 = red[8] + red[10], s2 = red[9] + red[11];
    float mu = s1 * (1.f / 128.f);
    float var = s2 * (1.f / 128.f) - mu * mu;
    float rinv = rsqrtf(var + 1e-5f);
    float pv = pp[0][tid] + pp[1][tid];
    normed[tid] = (pv - mu) * rinv * ln_g[tid] + ln_b[tid];
  }
  __syncthreads();

  if (tid < 2) {
    float a = fc_b[tid];
    for (int d2 = 0; d2 < 128; ++d2) a += normed[d2] * fc_w[tid * 128 + d2];
    res[b * 2 + tid] = a;
  }
}

extern "C" void kernel_launch(void* const* d_in, const int* in_sizes, int n_in,
                              void* d_out, int out_size, void* d_ws,
                              size_t ws_size, hipStream_t stream) {
  const float* x = (const float*)d_in[0];
  const float* conv_w = (const float*)d_in[1];
  const float* conv_b = (const float*)d_in[2];
  const float* w_ih_f = (const float*)d_in[3];
  const float* w_hh_f = (const float*)d_in[4];
  const float* b_f = (const float*)d_in[5];
  const float* w_ih_b = (const float*)d_in[6];
  const float* w_hh_b = (const float*)d_in[7];
  const float* b_b = (const float*)d_in[8];
  const float* attn_w = (const float*)d_in[9];
  const float* attn_b = (const float*)d_in[10];
  const float* ln_g = (const float*)d_in[11];
  const float* ln_b = (const float*)d_in[12];
  const float* fc_w = (const float*)d_in[13];
  const float* fc_b = (const float*)d_in[14];
  float* res = (float*)d_out;

  // ws layout (~68 MiB): xgP deleted (xg lives in the scan's LDS ring).
  char* ws = (char*)d_ws;
  ushort* wbT = (ushort*)ws;                       // 294,912 B
  ushort* wP = (ushort*)(ws + 0x60000);            // 131,072 B (bf16, scaled)
  ushort* whhP = (ushort*)(ws + 0x80000);          // 65,536 B (fp16, scaled)
  float* biasP = (float*)(ws + 0x90000);           // 2,048 B (scaled)
  ushort* y = (ushort*)(ws + 0x100000);            // 33,554,432 B (bf16)
  ushort* hout = (ushort*)(ws + 0x100000 + 33554432);  // 33,554,432 B (fp16)

  pack_w_kernel<<<576, 256, 0, stream>>>(conv_w, wbT);
  pack_wiP_kernel<<<256, 256, 0, stream>>>(w_ih_f, w_ih_b, wP);
  pack_whhP_kernel<<<128, 256, 0, stream>>>(w_hh_f, w_hh_b, whhP);
  pack_biasP_kernel<<<2, 256, 0, stream>>>(b_f, b_b, biasP);
  conv_gemm_kernel<<<B_ * (T_ / 128), 256, 0, stream>>>(x, wbT, conv_b, y);
  lstm_seq_kernel<<<128, 512, 0, stream>>>(whhP, wP, biasP, y, hout);
  head_kernel<<<B_, 256, 0, stream>>>(hout, attn_w, attn_b, ln_g, ln_b, fc_w,
                                      fc_b, res);
}

// Round 19
// 257.464 us; speedup vs baseline: 1.2588x; 1.1546x over previous
//
#include <hip/hip_runtime.h>
#include <hip/hip_fp16.h>
#include <math.h>

typedef unsigned int uint;
typedef unsigned short ushort;

#define B_ 256
#define T_ 512
#define F_ 378
#define C_ 128
#define H_ 64
#define KPAD 1152   // 3 * 384

using f32x4 = __attribute__((ext_vector_type(4))) float;
using bf16x8 = __attribute__((ext_vector_type(8))) short;
using f16x8 = __attribute__((ext_vector_type(8))) _Float16;

__device__ __forceinline__ ushort f2bf(float f) {
  union { float f; uint u; } c; c.f = f;
  uint r = (c.u + 0x7fffu + ((c.u >> 16) & 1u)) >> 16;
  return (ushort)r;
}
__device__ __forceinline__ uint packbf2(float a, float b) {
  return (uint)f2bf(a) | (((uint)f2bf(b)) << 16);
}
__device__ __forceinline__ ushort f2h(float f) {
  __half h = __float2half(f);
  return *(ushort*)&h;
}
__device__ __forceinline__ float h2f(ushort u) {
  __half h;
  *(ushort*)&h = u;
  return __half2float(h);
}
#define SC_SIG -1.442695041f
#define SC_TANH 2.885390082f

// ---------------- merged pack kernel (4 former launches in one) ------------
// blocks 0..575: conv w -> wbT[c][kk], kk=k*384+f, bf16
// blocks 576..831: w_ih -> wP[dir][g''][128] bf16 pre-scaled
// blocks 832..959: w_hh -> whhP[dir][r][64] fp16 pre-scaled
// blocks 960..961: bias -> biasP[dir][g''] fp32 pre-scaled
__global__ __launch_bounds__(256) void pack_all_kernel(
    const float* __restrict__ w, const float* __restrict__ wif,
    const float* __restrict__ wib, const float* __restrict__ whf,
    const float* __restrict__ whb, const float* __restrict__ bf,
    const float* __restrict__ bb, ushort* __restrict__ wbT,
    ushort* __restrict__ wP, ushort* __restrict__ whhP,
    float* __restrict__ biasP) {
  const int blk = blockIdx.x;
  if (blk < 576) {
    int i = blk * 256 + threadIdx.x;
    if (i >= C_ * KPAD) return;
    int c = i / KPAD, kk = i - c * KPAD;
    int k = kk / 384, f = kk - k * 384;
    float v = (f < F_) ? w[c * (F_ * 3) + f * 3 + k] : 0.f;
    wbT[i] = f2bf(v);
  } else if (blk < 832) {
    int i = (blk - 576) * 256 + threadIdx.x;  // 65536
    int dir = i >> 15, rem = i & 32767;
    int gp = rem >> 7, k = rem & 127;
    int e = gp & 3, n = (gp >> 2) & 3, q = (gp >> 4) & 3, wv = gp >> 6;
    int u = 16 * wv + 4 * q + n;
    const float* src = dir ? wib : wif;
    float scale = (e == 2) ? SC_TANH : SC_SIG;
    wP[i] = f2bf(src[(e * 64 + u) * 128 + k] * scale);
  } else if (blk < 960) {
    int i = (blk - 832) * 256 + threadIdx.x;  // 32768
    int dir = i >> 14, rem = i & 16383;
    int r = rem >> 6, k = rem & 63;
    int e = r & 3, q = (r >> 2) & 3, n = (r >> 4) & 3, wv = r >> 6;
    int u = 16 * wv + 4 * q + n;
    const float* src = dir ? whb : whf;
    float scale = (e == 2) ? SC_TANH : SC_SIG;
    whhP[i] = f2h(src[(e * 64 + u) * 64 + k] * scale);
  } else {
    int i = (blk - 960) * 256 + threadIdx.x;  // 512
    if (i >= 512) return;
    int dir = i >> 8, gp = i & 255;
    int e = gp & 3, n = (gp >> 2) & 3, q = (gp >> 4) & 3, wv = gp >> 6;
    int u = 16 * wv + 4 * q + n;
    const float* src = dir ? bb : bf;
    float scale = (e == 2) ? SC_TANH : SC_SIG;
    biasP[i] = src[e * 64 + u] * scale;
  }
}

// ---------------- Conv1d as implicit GEMM, bf16 MFMA -----------------------
__global__ __launch_bounds__(256, 2) void conv_gemm_kernel(
    const float* __restrict__ x, const ushort* __restrict__ wbT,
    const float* __restrict__ bias, ushort* __restrict__ y) {
  __shared__ __align__(16) char xsb[130 * 128];
  __shared__ __align__(16) char bsb[128 * 384];
  const int tid = threadIdx.x;
  const int lane = tid & 63;
  const int wr = (tid >> 7) & 1;
  const int wc = (tid >> 6) & 1;
  const int b = blockIdx.x >> 2;
  const int t0 = (blockIdx.x & 3) << 7;

  f32x4 acc[4][4];
#pragma unroll
  for (int m = 0; m < 4; ++m)
#pragma unroll
    for (int n = 0; n < 4; ++n) acc[m][n] = (f32x4)(0.f);

  for (int fs = 0; fs < 6; ++fs) {
    __syncthreads();
    {
      auto stage_a = [&](int r, int h) {
        const int t = t0 - 1 + r;
        const bool ok = (t >= 0) && (t < T_);
        const float* srow = x + ((long)b * T_ + (ok ? t : 0)) * F_;
        const int fb = fs * 64 + h * 32;
        char* dst = xsb + r * 128;
        const int sw = (r & 7) << 4;
        uint pk[16];
        if (ok && fb + 31 < F_) {
#pragma unroll
          for (int j = 0; j < 16; ++j) {
            float2 v = *(const float2*)(srow + fb + 2 * j);
            pk[j] = packbf2(v.x, v.y);
          }
        } else {
#pragma unroll
          for (int j = 0; j < 16; ++j) {
            const int f = fb + 2 * j;
            float a = (ok && f < F_) ? srow[f] : 0.f;
            float c2 = (ok && f + 1 < F_) ? srow[f + 1] : 0.f;
            pk[j] = packbf2(a, c2);
          }
        }
#pragma unroll
        for (int j = 0; j < 4; ++j) {
          uint4 p = {pk[4 * j], pk[4 * j + 1], pk[4 * j + 2], pk[4 * j + 3]};
          *(uint4*)(dst + ((h * 64 + j * 16) ^ sw)) = p;
        }
      };
      stage_a(tid >> 1, tid & 1);
      if (tid < 4) stage_a(128 + (tid >> 1), tid & 1);
    }
    {
      const int c = tid >> 1, h = tid & 1;
      const ushort* src = wbT + c * KPAD + fs * 64 + h * 32;
      char* drow = bsb + c * 384;
      const int sw = (c & 7) << 4;
#pragma unroll
      for (int k = 0; k < 3; ++k)
#pragma unroll
        for (int j = 0; j < 4; ++j) {
          uint4 v = *(const uint4*)(src + k * 384 + j * 8);
          *(uint4*)(drow + k * 128 + ((h * 64 + j * 16) ^ sw)) = v;
        }
    }
    __syncthreads();

#pragma unroll
    for (int k = 0; k < 3; ++k) {
#pragma unroll
      for (int s = 0; s < 2; ++s) {
        bf16x8 af[4], bfx[4];
        const int ksub = s * 64 + ((lane >> 4) << 4);
#pragma unroll
        for (int m = 0; m < 4; ++m) {
          const int rr = wr * 64 + m * 16 + (lane & 15) + k;
          af[m] = *(const bf16x8*)(xsb + rr * 128 + (ksub ^ ((rr & 7) << 4)));
        }
#pragma unroll
        for (int n = 0; n < 4; ++n) {
          const int c = wc * 64 + n * 16 + (lane & 15);
          bfx[n] =
              *(const bf16x8*)(bsb + c * 384 + k * 128 + (ksub ^ ((c & 7) << 4)));
        }
#pragma unroll
        for (int m = 0; m < 4; ++m)
#pragma unroll
          for (int n = 0; n < 4; ++n)
            acc[m][n] = __builtin_amdgcn_mfma_f32_16x16x32_bf16(
                af[m], bfx[n], acc[m][n], 0, 0, 0);
      }
    }
  }

  __syncthreads();
  float bc[4];
#pragma unroll
  for (int n = 0; n < 4; ++n) bc[n] = bias[wc * 64 + n * 16 + (lane & 15)];
#pragma unroll
  for (int m = 0; m < 4; ++m) {
#pragma unroll
    for (int n = 0; n < 4; ++n) {
      const int col = wc * 64 + n * 16 + (lane & 15);
#pragma unroll
      for (int r = 0; r < 4; ++r) {
        const int row = wr * 64 + m * 16 + ((lane >> 4) << 2) + r;
        float v = acc[m][n][r] + bc[n];
        v = v > 0.f ? v : 0.f;
        *(ushort*)(bsb + row * 256 + ((col * 2) ^ ((row & 7) << 4))) = f2bf(v);
      }
    }
  }
  __syncthreads();
  const int w = tid >> 6;
#pragma unroll
  for (int p = 0; p < 8; ++p) {
    const int rowb = p * 16 + w * 4 + (lane >> 4);
    const int colb = (lane & 15) * 16;
    uint4 v = *(const uint4*)(bsb + rowb * 256 + (colb ^ ((rowb & 7) << 4)));
    *(uint4*)((char*)(y + ((long)b * T_ + t0 + rowb) * 128) + colb) = v;
  }
}

// ---------------- LSTM scan: producer-consumer wave specialization ---------
// 128 blocks (2 dir x 64 groups of 4 seqs), 8 waves. Waves 0-3 = consumer
// scan (replica-spread nonlin). Waves 4-7 = producers, BATCHED: 8 timesteps
// per round (2 back-to-back PROUNDs), then 8 barriers -- halves per-step
// producer addressing/issue overhead vs R18's 4-step rounds. Ring: consumer
// reads slots [8k,8k+8) while producer writes [8k+8,8k+16) -- disjoint
// halves of the 16-slot ring; writes complete >=1 barrier before first read.
union U2 { uint u; __half2 h2; };

#define CSTEP(J)                                                               \
  do {                                                                         \
    const int t_ = t0ph + (J);                                                 \
    const int p_ = t_ & 1;                                                     \
    const int slot_ = ((ph & 1) << 3) + (J);                                   \
    const uint2 cur = *(const uint2*)(xgL + slot_ * 2176 + cOffL);             \
    f16x8 bh0, bh1;                                                            \
    {                                                                          \
      const char* hb = hx + p_ * 576 + s * 144;                                \
      bh0 = *(const f16x8*)(hb + q * 16);                                      \
      bh1 = *(const f16x8*)(hb + 64 + q * 16);                                 \
    }                                                                          \
    f32x4 acc[4];                                                              \
    _Pragma("unroll") for (int n = 0; n < 4; ++n) {                            \
      acc[n] = __builtin_amdgcn_mfma_f32_16x16x32_f16(afA[n], bh0,             \
                                                      (f32x4)(0.f), 0, 0, 0);  \
      acc[n] =                                                                 \
          __builtin_amdgcn_mfma_f32_16x16x32_f16(afB[n], bh1, acc[n], 0, 0, 0);\
    }                                                                          \
    float ge[4];                                                               \
    _Pragma("unroll") for (int e = 0; e < 4; ++e) {                            \
      float v01 = (r & 1) ? acc[1][e] : acc[0][e];                             \
      float v23 = (r & 1) ? acc[3][e] : acc[2][e];                             \
      ge[e] = (r & 2) ? v23 : v01;                                             \
    }                                                                          \
    U2 ua, ub;                                                                 \
    ua.u = cur.x;                                                              \
    ub.u = cur.y;                                                              \
    float2 xif = __half22float2(ua.h2);                                        \
    float2 xgo = __half22float2(ub.h2);                                        \
    float gi = ge[0] + xif.x, gf = ge[1] + xif.y;                              \
    float gg = ge[2] + xgo.x, go = ge[3] + xgo.y;                              \
    float Ei = __builtin_amdgcn_exp2f(gi);                                     \
    float Ef = __builtin_amdgcn_exp2f(gf);                                     \
    float Eg = __builtin_amdgcn_exp2f(gg);                                     \
    float Eo = __builtin_amdgcn_exp2f(go);                                     \
    float sf = __builtin_amdgcn_rcpf(1.f + Ef);                                \
    float den = __builtin_amdgcn_rcpf((1.f + Ei) * (1.f + Eg));                \
    cst = fmaf(sf, cst, (Eg - 1.f) * den);                                     \
    float Ec = __builtin_amdgcn_exp2f(SC_TANH * cst);                          \
    float hval = (Ec - 1.f) * __builtin_amdgcn_rcpf((1.f + Eo) * (1.f + Ec));  \
    const ushort hu = f2h(hval);                                               \
    *(ushort*)(hx + (1 - p_) * 576 + s * 144 + ub_) = hu;                      \
    {                                                                          \
      const int gt = dir ? (T_ - 1 - t_) : t_;                                 \
      houtp[(long)gt * 128] = hu;                                              \
    }                                                                          \
    asm volatile("s_waitcnt lgkmcnt(0)" ::: "memory");                         \
    __builtin_amdgcn_sched_barrier(0);                                         \
    __builtin_amdgcn_s_barrier();                                              \
    __builtin_amdgcn_sched_barrier(0);                                         \
  } while (0)

#define PROUND(TP0, YF)                                                        \
  do {                                                                         \
    f32x4 pacc[4];                                                             \
    _Pragma("unroll") for (int n = 0; n < 4; ++n) pacc[n] = biasC[n];          \
    _Pragma("unroll") for (int kk = 0; kk < 4; ++kk) {                         \
      _Pragma("unroll") for (int n = 0; n < 4; ++n)                            \
        pacc[n] = __builtin_amdgcn_mfma_f32_16x16x32_bf16(wiA[n][kk], YF[kk],  \
                                                          pacc[n], 0, 0, 0);   \
    }                                                                          \
    {                                                                          \
      int tt = (TP0) + 8 + toff;                                               \
      tt = tt > T_ - 1 ? T_ - 1 : tt;                                          \
      const int dt = dir ? (T_ - 1 - tt) : tt;                                 \
      const char* yr = ybaseP + (long)dt * 256;                                \
      _Pragma("unroll") for (int kk = 0; kk < 4; ++kk)                         \
        YF[kk] = *(const bf16x8*)(yr + kk * 64 + qp * 16);                     \
    }                                                                          \
    {                                                                          \
      const int slot_ = ((TP0) + toff) & 15;                                   \
      char* wp_ = xgL + slot_ * 2176 + sP * 544 + 128 * pw + 8 * qp;           \
      _Pragma("unroll") for (int n = 0; n < 4; ++n) {                          \
        uint2 hv;                                                              \
        hv.x = (uint)f2h(pacc[n][0]) | ((uint)f2h(pacc[n][1]) << 16);          \
        hv.y = (uint)f2h(pacc[n][2]) | ((uint)f2h(pacc[n][3]) << 16);          \
        *(uint2*)(wp_ + 32 * n) = hv;                                          \
      }                                                                        \
    }                                                                          \
  } while (0)

#define PBAR                                                                   \
  do {                                                                         \
    asm volatile("s_waitcnt lgkmcnt(0)" ::: "memory");                         \
    __builtin_amdgcn_sched_barrier(0);                                         \
    __builtin_amdgcn_s_barrier();                                              \
    __builtin_amdgcn_sched_barrier(0);                                         \
  } while (0)

__global__ __launch_bounds__(512, 1) void lstm_seq_kernel(
    const ushort* __restrict__ whhP, const ushort* __restrict__ wP,
    const float* __restrict__ biasP, const ushort* __restrict__ y,
    ushort* __restrict__ hout) {
  const int dir = blockIdx.x >> 6;
  const int bg = blockIdx.x & 63;
  const int tid = threadIdx.x;
  const int lane = tid & 63;
  const int wv = tid >> 6;  // 0..3 consumer, 4..7 producer

  __shared__ __align__(16) char xgL[16 * 2176];  // 34816 B ring
  __shared__ __align__(16) char hx[2 * 576];
  for (int i = tid; i < 288; i += 512) ((uint*)hx)[i] = 0u;

  if (wv < 4) {
    // ---------------- consumer ----------------
    const int w = wv;
    const int c = lane & 15;
    const int q = lane >> 4;
    const int s = c & 3;
    const int r = c >> 2;

    f16x8 afA[4], afB[4];
    {
      const ushort* base = whhP + (long)dir * 256 * 64;
#pragma unroll
      for (int n = 0; n < 4; ++n) {
        const ushort* rp = base + (64 * w + 16 * n + c) * 64 + q * 8;
        afA[n] = *(const f16x8*)rp;
        afB[n] = *(const f16x8*)(rp + 32);
      }
    }

    const int b = bg * 4 + s;
    const int u = 16 * w + 4 * q + r;
    const int ub_ = u * 2;
    const int cOffL = s * 544 + 128 * w + 32 * q + 8 * r;
    ushort* houtp = hout + (long)b * T_ * 128 + dir * 64 + u;

    float cst = 0.f;

    __syncthreads();  // producers filled slots 0..7

#pragma unroll 1
    for (int ph = 0; ph < 64; ++ph) {
      const int t0ph = ph * 8;
      CSTEP(0);
      CSTEP(1);
      CSTEP(2);
      CSTEP(3);
      CSTEP(4);
      CSTEP(5);
      CSTEP(6);
      CSTEP(7);
    }
  } else {
    // ---------------- producer ----------------
    const int pw = wv - 4;
    const int sP = lane & 3;
    const int toff = (lane >> 2) & 3;
    const int qp = lane >> 4;

    bf16x8 wiA[4][4];
    {
      const ushort* base2 = wP + (long)dir * 256 * 128;
#pragma unroll
      for (int n = 0; n < 4; ++n)
#pragma unroll
        for (int kk = 0; kk < 4; ++kk)
          wiA[n][kk] = *(const bf16x8*)(base2 +
                                        (64 * pw + 16 * n + (lane & 15)) * 128 +
                                        32 * kk + 8 * qp);
    }
    f32x4 biasC[4];
#pragma unroll
    for (int n = 0; n < 4; ++n)
      biasC[n] =
          *(const f32x4*)(biasP + dir * 256 + 64 * pw + 16 * n + 4 * qp);

    const int b = bg * 4 + sP;
    const char* ybaseP = (const char*)y + (long)b * T_ * 256 + 0;

    bf16x8 yfA[4], yfB[4];
    {
      int tt = 0 + toff;
      const int dt = dir ? (T_ - 1 - tt) : tt;
      const char* yr = ybaseP + (long)dt * 256;
#pragma unroll
      for (int kk = 0; kk < 4; ++kk)
        yfA[kk] = *(const bf16x8*)(yr + kk * 64 + qp * 16);
    }
    {
      int tt = 4 + toff;
      const int dt = dir ? (T_ - 1 - tt) : tt;
      const char* yr = ybaseP + (long)dt * 256;
#pragma unroll
      for (int kk = 0; kk < 4; ++kk)
        yfB[kk] = *(const bf16x8*)(yr + kk * 64 + qp * 16);
    }
    // prologue: fill slots 0..7; yfA<-t8..11, yfB<-t12..15
    PROUND(0, yfA);
    PROUND(4, yfB);

    __syncthreads();  // consumers may start

#pragma unroll 1
    for (int ph = 0; ph < 64; ++ph) {
      const int tp0 = ph * 8 + 8;
      PROUND(tp0, yfA);
      PROUND(tp0 + 4, yfB);
      PBAR;
      PBAR;
      PBAR;
      PBAR;
      PBAR;
      PBAR;
      PBAR;
      PBAR;
    }
  }
}

// ---------------- Attention pool + LayerNorm + FC (fp16 hio) ---------------
__global__ __launch_bounds__(256) void head_kernel(
    const ushort* __restrict__ hio, const float* __restrict__ attn_w,
    const float* __restrict__ attn_b, const float* __restrict__ ln_g,
    const float* __restrict__ ln_b, const float* __restrict__ fc_w,
    const float* __restrict__ fc_b, float* __restrict__ res) {
  const int b = blockIdx.x;
  const int tid = threadIdx.x;
  __shared__ __align__(16) float aw[128];
  __shared__ float l[T_];
  __shared__ float red[16];
  __shared__ float pp[2][128];
  __shared__ float normed[128];
  if (tid < 128) aw[tid] = attn_w[tid];
  __syncthreads();
  const float ab = attn_b[0];

  for (int t = tid; t < T_; t += 256) {
    const ushort* row = hio + ((long)b * T_ + t) * 128;
    float a = ab;
#pragma unroll
    for (int d = 0; d < 128; d += 8) {
      uint4 v = *(const uint4*)(row + d);
      float2 p0 = __half22float2(*(const __half2*)&v.x);
      float2 p1 = __half22float2(*(const __half2*)&v.y);
      float2 p2 = __half22float2(*(const __half2*)&v.z);
      float2 p3 = __half22float2(*(const __half2*)&v.w);
      a += p0.x * aw[d] + p0.y * aw[d + 1] + p1.x * aw[d + 2] +
           p1.y * aw[d + 3] + p2.x * aw[d + 4] + p2.y * aw[d + 5] +
           p3.x * aw[d + 6] + p3.y * aw[d + 7];
    }
    l[t] = a;
  }
  __syncthreads();

  float v0 = l[tid], v1 = l[tid + 256];
  float m = fmaxf(v0, v1);
#pragma unroll
  for (int off = 32; off >= 1; off >>= 1) m = fmaxf(m, __shfl_xor(m, off));
  if ((tid & 63) == 0) red[tid >> 6] = m;
  __syncthreads();
  m = fmaxf(fmaxf(red[0], red[1]), fmaxf(red[2], red[3]));
  float e0 = __expf(v0 - m), e1 = __expf(v1 - m);
  float ssum = e0 + e1;
#pragma unroll
  for (int off = 32; off >= 1; off >>= 1) ssum += __shfl_xor(ssum, off);
  if ((tid & 63) == 0) red[4 + (tid >> 6)] = ssum;
  __syncthreads();
  float inv = 1.f / (red[4] + red[5] + red[6] + red[7]);
  l[tid] = e0 * inv;
  l[tid + 256] = e1 * inv;
  __syncthreads();

  const int d = tid & 127, half = tid >> 7;
  float p = 0.f;
  for (int t = half * 256; t < half * 256 + 256; ++t)
    p += l[t] * h2f(hio[((long)b * T_ + t) * 128 + d]);
  pp[half][d] = p;
  __syncthreads();

  if (tid < 128) {
    float pv = pp[0][tid] + pp[1][tid];
    float s1 = pv, s2 = pv * pv;
#pragma unroll
    for (int off = 32; off >= 1; off >>= 1) {
      s1 += __shfl_xor(s1, off);
      s2 += __shfl_xor(s2, off);
    }
    if ((tid & 63) == 0) {
      red[8 + (tid >> 6) * 2] = s1;
      red[9 + (tid >> 6) * 2] = s2;
    }
  }
  __syncthreads();
  if (tid < 128) {
    float s1 = red[8] + red[10], s2 = red[9] + red[11];
    float mu = s1 * (1.f / 128.f);
    float var = s2 * (1.f / 128.f) - mu * mu;
    float rinv = rsqrtf(var + 1e-5f);
    float pv = pp[0][tid] + pp[1][tid];
    normed[tid] = (pv - mu) * rinv * ln_g[tid] + ln_b[tid];
  }
  __syncthreads();

  if (tid < 2) {
    float a = fc_b[tid];
    for (int d2 = 0; d2 < 128; ++d2) a += normed[d2] * fc_w[tid * 128 + d2];
    res[b * 2 + tid] = a;
  }
}

extern "C" void kernel_launch(void* const* d_in, const int* in_sizes, int n_in,
                              void* d_out, int out_size, void* d_ws,
                              size_t ws_size, hipStream_t stream) {
  const float* x = (const float*)d_in[0];
  const float* conv_w = (const float*)d_in[1];
  const float* conv_b = (const float*)d_in[2];
  const float* w_ih_f = (const float*)d_in[3];
  const float* w_hh_f = (const float*)d_in[4];
  const float* b_f = (const float*)d_in[5];
  const float* w_ih_b = (const float*)d_in[6];
  const float* w_hh_b = (const float*)d_in[7];
  const float* b_b = (const float*)d_in[8];
  const float* attn_w = (const float*)d_in[9];
  const float* attn_b = (const float*)d_in[10];
  const float* ln_g = (const float*)d_in[11];
  const float* ln_b = (const float*)d_in[12];
  const float* fc_w = (const float*)d_in[13];
  const float* fc_b = (const float*)d_in[14];
  float* res = (float*)d_out;

  // ws layout (~68 MiB):
  char* ws = (char*)d_ws;
  ushort* wbT = (ushort*)ws;                       // 294,912 B
  ushort* wP = (ushort*)(ws + 0x60000);            // 131,072 B (bf16, scaled)
  ushort* whhP = (ushort*)(ws + 0x80000);          // 65,536 B (fp16, scaled)
  float* biasP = (float*)(ws + 0x90000);           // 2,048 B (scaled)
  ushort* y = (ushort*)(ws + 0x100000);            // 33,554,432 B (bf16)
  ushort* hout = (ushort*)(ws + 0x100000 + 33554432);  // 33,554,432 B (fp16)

  pack_all_kernel<<<962, 256, 0, stream>>>(conv_w, w_ih_f, w_ih_b, w_hh_f,
                                           w_hh_b, b_f, b_b, wbT, wP, whhP,
                                           biasP);
  conv_gemm_kernel<<<B_ * (T_ / 128), 256, 0, stream>>>(x, wbT, conv_b, y);
  lstm_seq_kernel<<<128, 512, 0, stream>>>(whhP, wP, biasP, y, hout);
  head_kernel<<<B_, 256, 0, stream>>>(hout, attn_w, attn_b, ln_g, ln_b, fc_w,
                                      fc_b, res);
}